// Round 4
// baseline (81805.804 us; speedup 1.0000x reference)
//
#include <hip/hip_runtime.h>
#include <hip/hip_bf16.h>

#define LN_EPS 1e-5f

typedef __attribute__((ext_vector_type(4))) float    f32x4;
typedef __attribute__((ext_vector_type(8))) short    s16x8;
typedef __attribute__((ext_vector_type(4))) unsigned u32x4;

__device__ __forceinline__ float sigmoidf_(float x){ return 1.0f/(1.0f+expf(-x)); }

__device__ __forceinline__ short bf16_hi_bits(float f){
  __hip_bfloat16 h = __float2bfloat16(f);
  return *reinterpret_cast<short*>(&h);
}
__device__ __forceinline__ float bf16_hi_val(float f){
  return __bfloat162float(__float2bfloat16(f));
}

// ---------------------------------------------------------------------------
// bn1: per-channel (V=128) stats over B*T=16384 rows of x[b][t][v]
// ---------------------------------------------------------------------------
__global__ void k_bn1_stats(const float* __restrict__ x, float* __restrict__ stats){
  int tid = threadIdx.x;
  int cg = tid >> 3, ro = tid & 7;
  int c4 = cg * 4;
  float s[4] = {0,0,0,0}, q[4] = {0,0,0,0};
  int rbase = blockIdx.x * 64;
  for (int i = 0; i < 8; ++i){
    int row = rbase + i*8 + ro;
    f32x4 v = *(const f32x4*)(x + (size_t)row*128 + c4);
    #pragma unroll
    for (int e=0;e<4;e++){ s[e]+=v[e]; q[e]+=v[e]*v[e]; }
  }
  #pragma unroll
  for (int o=1;o<8;o<<=1){
    #pragma unroll
    for (int e=0;e<4;e++){ s[e]+=__shfl_xor(s[e],o); q[e]+=__shfl_xor(q[e],o); }
  }
  if (ro==0){
    #pragma unroll
    for (int e=0;e<4;e++){
      atomicAdd(&stats[c4+e], s[e]);
      atomicAdd(&stats[128+c4+e], q[e]);
    }
  }
}

__global__ void k_bn1_fin(const float* __restrict__ stats, const float* __restrict__ gamma,
                          const float* __restrict__ beta, float* __restrict__ ss){
  int c = threadIdx.x;
  if (c < 128){
    float N = 16384.0f;
    float mean = stats[c]/N;
    float var  = stats[128+c]/N - mean*mean;
    float scale = gamma[c] * rsqrtf(var + LN_EPS);
    ss[c] = scale;
    ss[128+c] = beta[c] - mean*scale;
  }
}

// split f32 -> (hi, lo) bf16 pair
__global__ void k_cvt_split(const float* __restrict__ s, __hip_bfloat16* __restrict__ hi,
                            __hip_bfloat16* __restrict__ lo, int n){
  for (int i = blockIdx.x*blockDim.x + threadIdx.x; i < n; i += gridDim.x*blockDim.x){
    float v = s[i];
    __hip_bfloat16 h = __float2bfloat16(v);
    hi[i] = h;
    lo[i] = __float2bfloat16(v - __bfloat162float(h));
  }
}

// ---------------------------------------------------------------------------
// Split-bf16 fp32-accurate GEMM: C[M][N] = A[M][K] * B[N][K]^T, C fp16.
// A fp32 source, split in staging. a_mode==1: A[m][k] = x[b][t][k]*ss[k]+ss[128+k]
// with m = t*32+b (K=128). B pre-split hi/lo bf16.
// 128x128 tile, BK=32, 256 threads.
// ---------------------------------------------------------------------------
__global__ __launch_bounds__(256) void gemm_split(const float* __restrict__ A,
                                                  const __hip_bfloat16* __restrict__ Bhi,
                                                  const __hip_bfloat16* __restrict__ Blo,
                                                  _Float16* __restrict__ C,
                                                  int M, int N, int K,
                                                  int a_mode, const float* __restrict__ ss){
  __shared__ __align__(16) __hip_bfloat16 Ah[128*32];
  __shared__ __align__(16) __hip_bfloat16 Al[128*32];
  __shared__ __align__(16) __hip_bfloat16 Bh[128*32];
  __shared__ __align__(16) __hip_bfloat16 Bl[128*32];
  int n0 = blockIdx.x * 128, m0 = blockIdx.y * 128;
  int tid = threadIdx.x, lane = tid & 63, wave = tid >> 6;
  int wm = wave >> 1, wn = wave & 1;
  f32x4 acc[4][4] = {};
  int r = tid >> 2, sseg = tid & 3;
  for (int kt = 0; kt < K; kt += 32){
    #pragma unroll
    for (int half = 0; half < 2; ++half){
      int m = m0 + half*64 + r;
      const float* src;
      if (a_mode){
        int t = m >> 5, b = m & 31;
        src = A + ((size_t)(b*512 + t))*128 + kt + sseg*8;
      } else {
        src = A + (size_t)m*K + kt + sseg*8;
      }
      f32x4 v0 = *(const f32x4*)src;
      f32x4 v1 = *(const f32x4*)(src + 4);
      s16x8 vh, vl;
      #pragma unroll
      for (int e=0;e<4;e++){
        float f0 = v0[e], f1 = v1[e];
        if (a_mode){
          int k = kt + sseg*8;
          f0 = f0*ss[k+e]   + ss[128+k+e];
          f1 = f1*ss[k+4+e] + ss[128+k+4+e];
        }
        float h0 = bf16_hi_val(f0), h1 = bf16_hi_val(f1);
        vh[e]   = bf16_hi_bits(f0); vl[e]   = bf16_hi_bits(f0 - h0);
        vh[4+e] = bf16_hi_bits(f1); vl[4+e] = bf16_hi_bits(f1 - h1);
      }
      *(s16x8*)&Ah[(half*64+r)*32 + sseg*8] = vh;
      *(s16x8*)&Al[(half*64+r)*32 + sseg*8] = vl;
      u32x4 bh = *(const u32x4*)(Bhi + (size_t)(n0 + half*64 + r)*K + kt + sseg*8);
      u32x4 bl = *(const u32x4*)(Blo + (size_t)(n0 + half*64 + r)*K + kt + sseg*8);
      *(u32x4*)&Bh[(half*64+r)*32 + sseg*8] = bh;
      *(u32x4*)&Bl[(half*64+r)*32 + sseg*8] = bl;
    }
    __syncthreads();
    s16x8 afh[4], afl[4], bfh[4], bfl[4];
    int k8 = (lane >> 4) * 8;
    int ra = wm*64 + (lane & 15), rb = wn*64 + (lane & 15);
    #pragma unroll
    for (int mi=0;mi<4;mi++){
      afh[mi] = *(const s16x8*)&Ah[(ra + mi*16)*32 + k8];
      afl[mi] = *(const s16x8*)&Al[(ra + mi*16)*32 + k8];
    }
    #pragma unroll
    for (int ni=0;ni<4;ni++){
      bfh[ni] = *(const s16x8*)&Bh[(rb + ni*16)*32 + k8];
      bfl[ni] = *(const s16x8*)&Bl[(rb + ni*16)*32 + k8];
    }
    #pragma unroll
    for (int mi=0;mi<4;mi++)
      #pragma unroll
      for (int ni=0;ni<4;ni++){
        acc[mi][ni] = __builtin_amdgcn_mfma_f32_16x16x32_bf16(afh[mi], bfh[ni], acc[mi][ni], 0, 0, 0);
        acc[mi][ni] = __builtin_amdgcn_mfma_f32_16x16x32_bf16(afl[mi], bfh[ni], acc[mi][ni], 0, 0, 0);
        acc[mi][ni] = __builtin_amdgcn_mfma_f32_16x16x32_bf16(afh[mi], bfl[ni], acc[mi][ni], 0, 0, 0);
      }
    __syncthreads();
  }
  #pragma unroll
  for (int mi=0;mi<4;mi++)
    #pragma unroll
    for (int ni=0;ni<4;ni++){
      int col  = n0 + wn*64 + ni*16 + (lane & 15);
      int row0 = m0 + wm*64 + mi*16 + (lane >> 4)*4;
      #pragma unroll
      for (int rr=0;rr<4;rr++)
        C[(size_t)(row0+rr)*N + col] = (_Float16)acc[mi][ni][rr];
    }
}

// ---------------------------------------------------------------------------
// LSTM layer (cooperative, custom grid barrier). fp32 compute, fp16 xp input.
// ---------------------------------------------------------------------------
__device__ __forceinline__ void grid_barrier(unsigned* cnt, unsigned* epoch, unsigned target){
  __syncthreads();
  if (threadIdx.x == 0){
    __threadfence();
    unsigned pos = atomicAdd(cnt, 1u);
    if (pos == gridDim.x - 1){
      atomicExch(cnt, 0u);
      __threadfence();
      atomicAdd(epoch, 1u);
    } else {
      while (__hip_atomic_load(epoch, __ATOMIC_RELAXED, __HIP_MEMORY_SCOPE_AGENT) < target)
        __builtin_amdgcn_s_sleep(2);
    }
    __threadfence();
  }
  __syncthreads();
}

__global__ __launch_bounds__(512) void lstm_layer(
    const _Float16* __restrict__ xp,         // [16384][4096] fp16
    const float* __restrict__ whh,           // [2][2048][512]
    const float* __restrict__ gg, const float* __restrict__ gb,
    const float* __restrict__ cgam, const float* __restrict__ cbet,
    float* __restrict__ h_buf,               // [2][32][512]
    float* __restrict__ pre_buf,             // [2][32][2048]
    float* __restrict__ pg,                  // [2][32][4][2][128]
    unsigned* __restrict__ bar,
    float* __restrict__ out)                 // [16384][1024]
{
  int wg = blockIdx.x;
  int dir = wg >> 7, slice = wg & 127;
  int tid = threadIdx.x;
  int b = tid >> 4, idx = tid & 15, g = idx >> 2, jj = idx & 3;
  int j = slice*4 + jj, col = g*512 + j;
  const float* wrow = whh + ((size_t)dir*2048 + col)*512;
  const float* hrow = h_buf + (dir*32 + b)*512;
  int dirB = wg >> 5, bB = wg & 31;

  __shared__ float c_lds[512];
  __shared__ float redg[16];
  __shared__ float redc[16];
  __shared__ float prestat[4][2];
  __shared__ float cst[2];
  if (wg < 64) c_lds[tid] = 0.0f;

  unsigned bar_t = 0;

  for (int t = 0; t < 512; ++t){
    int pos = dir ? (511 - t) : t;
    // -------- phase A: pre-activation slice + partial LN stats --------
    float acc = (float)xp[(size_t)(pos*32 + b)*4096 + dir*2048 + col];
    #pragma unroll 8
    for (int k = 0; k < 512; k += 4){
      f32x4 hv = *(const f32x4*)(hrow + k);
      f32x4 wv = *(const f32x4*)(wrow + k);
      acc += hv[0]*wv[0] + hv[1]*wv[1] + hv[2]*wv[2] + hv[3]*wv[3];
    }
    pre_buf[(size_t)(dir*32 + b)*2048 + col] = acc;
    float s = acc, q = acc*acc;
    s += __shfl_xor(s,1); q += __shfl_xor(q,1);
    s += __shfl_xor(s,2); q += __shfl_xor(q,2);
    if (jj == 0){
      float* base = pg + (size_t)(((dir*32 + b)*4 + g)*2)*128 + slice;
      base[0] = s; base[128] = q;
    }
    grid_barrier(bar, bar+1, ++bar_t);
    // -------- phase B (blocks 0..63): LN + gates + cell + h --------
    if (wg < 64){
      int wv = tid >> 6, ln = tid & 63;
      {
        const float* src = pg + (size_t)(((dirB*32 + bB)*4 + (wv>>1))*2 + (wv&1))*128;
        float v = src[ln] + src[ln + 64];
        #pragma unroll
        for (int o=1;o<64;o<<=1) v += __shfl_xor(v,o);
        if (ln == 0) redg[wv] = v;
      }
      __syncthreads();
      if (tid < 4){
        float ssum = redg[tid*2], sq = redg[tid*2+1];
        float mean = ssum*(1.0f/512.0f);
        float var  = sq*(1.0f/512.0f) - mean*mean;
        prestat[tid][0] = mean; prestat[tid][1] = rsqrtf(var + LN_EPS);
      }
      __syncthreads();
      int jB = tid;
      const float* prow = pre_buf + (size_t)(dirB*32 + bB)*2048;
      int gbase = dirB*2048;
      float pi = (prow[jB]      - prestat[0][0])*prestat[0][1]*gg[gbase+jB]      + gb[gbase+jB];
      float pf = (prow[512+jB]  - prestat[1][0])*prestat[1][1]*gg[gbase+512+jB]  + gb[gbase+512+jB];
      float pv = (prow[1024+jB] - prestat[2][0])*prestat[2][1]*gg[gbase+1024+jB] + gb[gbase+1024+jB];
      float po = (prow[1536+jB] - prestat[3][0])*prestat[3][1]*gg[gbase+1536+jB] + gb[gbase+1536+jB];
      float cn = sigmoidf_(pf)*c_lds[jB] + sigmoidf_(pi)*tanhf(pv);
      c_lds[jB] = cn;
      float cs = cn, cq = cn*cn;
      #pragma unroll
      for (int o=1;o<64;o<<=1){ cs += __shfl_xor(cs,o); cq += __shfl_xor(cq,o); }
      if (ln == 0){ redc[wv*2] = cs; redc[wv*2+1] = cq; }
      __syncthreads();
      if (tid == 0){
        float S=0,Q=0;
        #pragma unroll
        for (int i=0;i<8;i++){ S += redc[i*2]; Q += redc[i*2+1]; }
        float m = S*(1.0f/512.0f);
        float v = Q*(1.0f/512.0f) - m*m;
        cst[0] = m; cst[1] = rsqrtf(v + LN_EPS);
      }
      __syncthreads();
      float cl = (cn - cst[0])*cst[1]*cgam[dirB*512+jB] + cbet[dirB*512+jB];
      float hv = sigmoidf_(po) * tanhf(cl);
      h_buf[(dirB*32 + bB)*512 + jB] = hv;
      int posB = dirB ? (511 - t) : t;
      out[(size_t)(posB*32 + bB)*1024 + dirB*512 + jB] = hv;
    }
    grid_barrier(bar, bar+1, ++bar_t);
  }
}

// ---------------------------------------------------------------------------
__global__ void k_bn2_stats(const float* __restrict__ h1, float* __restrict__ stats){
  int tid = threadIdx.x;
  int c4 = tid*4;
  float s[4]={0,0,0,0}, q[4]={0,0,0,0};
  int rbase = blockIdx.x*64;
  for (int i=0;i<64;i++){
    f32x4 v = *(const f32x4*)(h1 + (size_t)(rbase+i)*1024 + c4);
    #pragma unroll
    for (int e=0;e<4;e++){ s[e]+=v[e]; q[e]+=v[e]*v[e]; }
  }
  #pragma unroll
  for (int e=0;e<4;e++){
    atomicAdd(&stats[c4+e], s[e]);
    atomicAdd(&stats[1024+c4+e], q[e]);
  }
}

__global__ void k_bn2_fin(const float* __restrict__ stats, const float* __restrict__ gamma,
                          const float* __restrict__ beta, float* __restrict__ ss){
  int c = blockIdx.x*256 + threadIdx.x;
  if (c < 1024){
    float N = 16384.0f;
    float mean = stats[c]/N;
    float var  = stats[1024+c]/N - mean*mean;
    float scale = gamma[c] * rsqrtf(var + LN_EPS);
    ss[c] = scale;
    ss[1024+c] = beta[c] - mean*scale;
  }
}

// vu[m] = (tanh(bn2(h1[m]) @ W + b)) . u
// 3 partial sums per attention feature, combined via LDS (shfl_down over 20
// was out-of-wave for lanes 44..59 -> doubled part-2; fixed with LDS combine).
__global__ void k_att1(const float* __restrict__ h1, const float* __restrict__ ss,
                       const float* __restrict__ wom, const float* __restrict__ bom,
                       const float* __restrict__ uom, float* __restrict__ vu){
  __shared__ float tmp[4][64];
  int tid = threadIdx.x, wave = tid >> 6, ln = tid & 63;
  int part = ln/20, a = ln - part*20;
  bool active = (part < 3);
  for (int rr = 0; rr < 4; ++rr){
    int row = blockIdx.x*16 + wave*4 + rr;
    float acc = 0.0f;
    if (active){
      int n0 = part*342, n1 = (part==2) ? 1024 : (n0+342);
      for (int n = n0; n < n1; ++n){
        float hv = h1[(size_t)row*1024 + n]*ss[n] + ss[1024+n];
        acc += hv * wom[n*20 + a];
      }
    }
    tmp[wave][ln] = acc;
    __syncthreads();
    float pv = 0.0f;
    if (ln < 20){
      float v = tanhf(tmp[wave][ln] + tmp[wave][ln+20] + tmp[wave][ln+40] + bom[ln]);
      pv = v*uom[ln];
    }
    #pragma unroll
    for (int o=1;o<32;o<<=1) pv += __shfl_xor(pv, o);
    if (ln == 0) vu[row] = pv;
    __syncthreads();
  }
}

__global__ void k_att3(const float* __restrict__ h1, const float* __restrict__ ss,
                       const float* __restrict__ vu, float* __restrict__ out){
  __shared__ float al[512];
  __shared__ float red[4];
  int tid = threadIdx.x;
  int b = blockIdx.x >> 3, ch = blockIdx.x & 7;
  for (int t = tid; t < 512; t += 128) al[t] = vu[t*32 + b];
  __syncthreads();
  float m = -1e30f;
  for (int t = tid; t < 512; t += 128) m = fmaxf(m, al[t]);
  #pragma unroll
  for (int o=1;o<64;o<<=1) m = fmaxf(m, __shfl_xor(m,o));
  if ((tid & 63) == 0) red[tid>>6] = m;
  __syncthreads();
  m = fmaxf(red[0], red[1]);
  float s = 0.0f;
  for (int t = tid; t < 512; t += 128){ float e = expf(al[t]-m); al[t] = e; s += e; }
  #pragma unroll
  for (int o=1;o<64;o<<=1) s += __shfl_xor(s,o);
  if ((tid & 63) == 0) red[2 + (tid>>6)] = s;
  __syncthreads();
  float inv = 1.0f / (red[2] + red[3]);
  int n = ch*128 + tid;
  float acc = 0.0f;
  #pragma unroll 4
  for (int t = 0; t < 512; ++t) acc += al[t]*h1[(size_t)(t*32+b)*1024 + n];
  out[b*1024 + n] = acc*inv*ss[n] + ss[1024+n];
}

// ---------------------------------------------------------------------------
extern "C" void kernel_launch(void* const* d_in, const int* in_sizes, int n_in,
                              void* d_out, int out_size, void* d_ws, size_t ws_size,
                              hipStream_t stream){
  const float* x    = (const float*)d_in[0];
  const float* bn1g = (const float*)d_in[1];
  const float* bn1b = (const float*)d_in[2];
  const float* bn2g = (const float*)d_in[3];
  const float* bn2b = (const float*)d_in[4];
  const float* wih0 = (const float*)d_in[5];
  const float* whh0 = (const float*)d_in[6];
  const float* gg0  = (const float*)d_in[7];
  const float* gb0  = (const float*)d_in[8];
  const float* cg0  = (const float*)d_in[9];
  const float* cb0  = (const float*)d_in[10];
  const float* wih1 = (const float*)d_in[11];
  const float* whh1 = (const float*)d_in[12];
  const float* gg1  = (const float*)d_in[13];
  const float* gb1  = (const float*)d_in[14];
  const float* cg1  = (const float*)d_in[15];
  const float* cb1  = (const float*)d_in[16];
  const float* wom  = (const float*)d_in[17];
  const float* bom  = (const float*)d_in[18];
  const float* uom  = (const float*)d_in[19];
  float* out = (float*)d_out;

  char* w = (char*)d_ws;
  size_t off = 0;
  auto take = [&](size_t bytes)->void*{
    void* p = w + off;
    off += (bytes + 255) & ~(size_t)255;
    return p;
  };
  _Float16* xp = (_Float16*)take(16384ull*4096*2);      // 128 MB (both layers)
  float* hA = (float*)take(16384ull*1024*4);            // 64 MB (h0, then h1)
  __hip_bfloat16* w0hi = (__hip_bfloat16*)take(4096ull*128*2);
  __hip_bfloat16* w0lo = (__hip_bfloat16*)take(4096ull*128*2);
  __hip_bfloat16* w1hi = (__hip_bfloat16*)take(4096ull*1024*2);
  __hip_bfloat16* w1lo = (__hip_bfloat16*)take(4096ull*1024*2);
  float* hbuf   = (float*)take(2ull*32*512*4);
  unsigned* bar = (unsigned*)take(256);
  float* prebuf = (float*)take(2ull*32*2048*4);
  float* pgbuf  = (float*)take(2ull*32*4*2*128*4);
  float* stats1 = (float*)take(256*4);
  float* ss1    = (float*)take(256*4);
  float* stats2 = (float*)take(2048*4);
  float* ss2    = (float*)take(2048*4);
  float* vu     = (float*)take(16384ull*4);
  (void)ws_size; (void)in_sizes; (void)n_in; (void)out_size;

  hipMemsetAsync(stats1, 0, 256*4, stream);
  hipMemsetAsync(stats2, 0, 2048*4, stream);

  k_bn1_stats<<<256,256,0,stream>>>(x, stats1);
  k_bn1_fin<<<1,128,0,stream>>>(stats1, bn1g, bn1b, ss1);
  k_cvt_split<<<256,256,0,stream>>>(wih0, w0hi, w0lo, 4096*128);
  k_cvt_split<<<2048,256,0,stream>>>(wih1, w1hi, w1lo, 4096*1024);

  // GEMM0: xp = bn1(x) @ w_ih0^T   (A from x with on-the-fly bn+split, K=128)
  gemm_split<<<dim3(32,128),256,0,stream>>>(x, w0hi, w0lo, xp, 16384, 4096, 128, 1, ss1);

  // ---- layer 0 ----
  hipMemsetAsync(hbuf, 0, 2*32*512*4 + 256, stream);
  {
    const _Float16* xp_c = xp;
    const float *whh = whh0, *gg = gg0, *gb = gb0, *cgam = cg0, *cbet = cb0;
    float* o = hA;
    void* args[] = {(void*)&xp_c,(void*)&whh,(void*)&gg,(void*)&gb,(void*)&cgam,(void*)&cbet,
                    (void*)&hbuf,(void*)&prebuf,(void*)&pgbuf,(void*)&bar,(void*)&o};
    hipLaunchCooperativeKernel((const void*)lstm_layer, dim3(256), dim3(512), args, 0, stream);
  }

  // GEMM1: xp = h0 @ w_ih1^T  (A = hA fp32, K=1024)
  gemm_split<<<dim3(32,128),256,0,stream>>>(hA, w1hi, w1lo, xp, 16384, 4096, 1024, 0, nullptr);

  // ---- layer 1 ---- (output overwrites hA after GEMM1 consumed it)
  hipMemsetAsync(hbuf, 0, 2*32*512*4 + 256, stream);
  {
    const _Float16* xp_c = xp;
    const float *whh = whh1, *gg = gg1, *gb = gb1, *cgam = cg1, *cbet = cb1;
    float* o = hA;
    void* args[] = {(void*)&xp_c,(void*)&whh,(void*)&gg,(void*)&gb,(void*)&cgam,(void*)&cbet,
                    (void*)&hbuf,(void*)&prebuf,(void*)&pgbuf,(void*)&bar,(void*)&o};
    hipLaunchCooperativeKernel((const void*)lstm_layer, dim3(256), dim3(512), args, 0, stream);
  }

  k_bn2_stats<<<256,256,0,stream>>>(hA, stats2);
  k_bn2_fin<<<4,256,0,stream>>>(stats2, bn2g, bn2b, ss2);
  k_att1<<<1024,256,0,stream>>>(hA, ss2, wom, bom, uom, vu);
  k_att3<<<256,128,0,stream>>>(hA, ss2, vu, out);
}

// Round 5
// 53953.632 us; speedup vs baseline: 1.5162x; 1.5162x over previous
//
#include <hip/hip_runtime.h>
#include <hip/hip_bf16.h>

#define LN_EPS 1e-5f

typedef __attribute__((ext_vector_type(4))) float    f32x4;
typedef __attribute__((ext_vector_type(8))) short    s16x8;
typedef __attribute__((ext_vector_type(4))) unsigned u32x4;

__device__ __forceinline__ float sigmoidf_(float x){ return 1.0f/(1.0f+expf(-x)); }

__device__ __forceinline__ short bf16_hi_bits(float f){
  __hip_bfloat16 h = __float2bfloat16(f);
  return *reinterpret_cast<short*>(&h);
}
__device__ __forceinline__ float bf16_hi_val(float f){
  return __bfloat162float(__float2bfloat16(f));
}

// LLC-coherent (agent-scope, cache-bypassing) accessors for cross-block data.
__device__ __forceinline__ float agent_load(const float* p){
  return __hip_atomic_load((float*)p, __ATOMIC_RELAXED, __HIP_MEMORY_SCOPE_AGENT);
}
__device__ __forceinline__ void agent_store(float* p, float v){
  __hip_atomic_store(p, v, __ATOMIC_RELAXED, __HIP_MEMORY_SCOPE_AGENT);
}

// ---------------------------------------------------------------------------
// bn1: per-channel (V=128) stats over B*T=16384 rows of x[b][t][v]
// ---------------------------------------------------------------------------
__global__ void k_bn1_stats(const float* __restrict__ x, float* __restrict__ stats){
  int tid = threadIdx.x;
  int cg = tid >> 3, ro = tid & 7;
  int c4 = cg * 4;
  float s[4] = {0,0,0,0}, q[4] = {0,0,0,0};
  int rbase = blockIdx.x * 64;
  for (int i = 0; i < 8; ++i){
    int row = rbase + i*8 + ro;
    f32x4 v = *(const f32x4*)(x + (size_t)row*128 + c4);
    #pragma unroll
    for (int e=0;e<4;e++){ s[e]+=v[e]; q[e]+=v[e]*v[e]; }
  }
  #pragma unroll
  for (int o=1;o<8;o<<=1){
    #pragma unroll
    for (int e=0;e<4;e++){ s[e]+=__shfl_xor(s[e],o); q[e]+=__shfl_xor(q[e],o); }
  }
  if (ro==0){
    #pragma unroll
    for (int e=0;e<4;e++){
      atomicAdd(&stats[c4+e], s[e]);
      atomicAdd(&stats[128+c4+e], q[e]);
    }
  }
}

__global__ void k_bn1_fin(const float* __restrict__ stats, const float* __restrict__ gamma,
                          const float* __restrict__ beta, float* __restrict__ ss){
  int c = threadIdx.x;
  if (c < 128){
    float N = 16384.0f;
    float mean = stats[c]/N;
    float var  = stats[128+c]/N - mean*mean;
    float scale = gamma[c] * rsqrtf(var + LN_EPS);
    ss[c] = scale;
    ss[128+c] = beta[c] - mean*scale;
  }
}

// split f32 -> (hi, lo) bf16 pair
__global__ void k_cvt_split(const float* __restrict__ s, __hip_bfloat16* __restrict__ hi,
                            __hip_bfloat16* __restrict__ lo, int n){
  for (int i = blockIdx.x*blockDim.x + threadIdx.x; i < n; i += gridDim.x*blockDim.x){
    float v = s[i];
    __hip_bfloat16 h = __float2bfloat16(v);
    hi[i] = h;
    lo[i] = __float2bfloat16(v - __bfloat162float(h));
  }
}

// ---------------------------------------------------------------------------
// Split-bf16 fp32-accurate GEMM: C[M][N] = A[M][K] * B[N][K]^T, C fp16.
// ---------------------------------------------------------------------------
__global__ __launch_bounds__(256) void gemm_split(const float* __restrict__ A,
                                                  const __hip_bfloat16* __restrict__ Bhi,
                                                  const __hip_bfloat16* __restrict__ Blo,
                                                  _Float16* __restrict__ C,
                                                  int M, int N, int K,
                                                  int a_mode, const float* __restrict__ ss){
  __shared__ __align__(16) __hip_bfloat16 Ah[128*32];
  __shared__ __align__(16) __hip_bfloat16 Al[128*32];
  __shared__ __align__(16) __hip_bfloat16 Bh[128*32];
  __shared__ __align__(16) __hip_bfloat16 Bl[128*32];
  int n0 = blockIdx.x * 128, m0 = blockIdx.y * 128;
  int tid = threadIdx.x, lane = tid & 63, wave = tid >> 6;
  int wm = wave >> 1, wn = wave & 1;
  f32x4 acc[4][4] = {};
  int r = tid >> 2, sseg = tid & 3;
  for (int kt = 0; kt < K; kt += 32){
    #pragma unroll
    for (int half = 0; half < 2; ++half){
      int m = m0 + half*64 + r;
      const float* src;
      if (a_mode){
        int t = m >> 5, b = m & 31;
        src = A + ((size_t)(b*512 + t))*128 + kt + sseg*8;
      } else {
        src = A + (size_t)m*K + kt + sseg*8;
      }
      f32x4 v0 = *(const f32x4*)src;
      f32x4 v1 = *(const f32x4*)(src + 4);
      s16x8 vh, vl;
      #pragma unroll
      for (int e=0;e<4;e++){
        float f0 = v0[e], f1 = v1[e];
        if (a_mode){
          int k = kt + sseg*8;
          f0 = f0*ss[k+e]   + ss[128+k+e];
          f1 = f1*ss[k+4+e] + ss[128+k+4+e];
        }
        float h0 = bf16_hi_val(f0), h1 = bf16_hi_val(f1);
        vh[e]   = bf16_hi_bits(f0); vl[e]   = bf16_hi_bits(f0 - h0);
        vh[4+e] = bf16_hi_bits(f1); vl[4+e] = bf16_hi_bits(f1 - h1);
      }
      *(s16x8*)&Ah[(half*64+r)*32 + sseg*8] = vh;
      *(s16x8*)&Al[(half*64+r)*32 + sseg*8] = vl;
      u32x4 bh = *(const u32x4*)(Bhi + (size_t)(n0 + half*64 + r)*K + kt + sseg*8);
      u32x4 bl = *(const u32x4*)(Blo + (size_t)(n0 + half*64 + r)*K + kt + sseg*8);
      *(u32x4*)&Bh[(half*64+r)*32 + sseg*8] = bh;
      *(u32x4*)&Bl[(half*64+r)*32 + sseg*8] = bl;
    }
    __syncthreads();
    s16x8 afh[4], afl[4], bfh[4], bfl[4];
    int k8 = (lane >> 4) * 8;
    int ra = wm*64 + (lane & 15), rb = wn*64 + (lane & 15);
    #pragma unroll
    for (int mi=0;mi<4;mi++){
      afh[mi] = *(const s16x8*)&Ah[(ra + mi*16)*32 + k8];
      afl[mi] = *(const s16x8*)&Al[(ra + mi*16)*32 + k8];
    }
    #pragma unroll
    for (int ni=0;ni<4;ni++){
      bfh[ni] = *(const s16x8*)&Bh[(rb + ni*16)*32 + k8];
      bfl[ni] = *(const s16x8*)&Bl[(rb + ni*16)*32 + k8];
    }
    #pragma unroll
    for (int mi=0;mi<4;mi++)
      #pragma unroll
      for (int ni=0;ni<4;ni++){
        acc[mi][ni] = __builtin_amdgcn_mfma_f32_16x16x32_bf16(afh[mi], bfh[ni], acc[mi][ni], 0, 0, 0);
        acc[mi][ni] = __builtin_amdgcn_mfma_f32_16x16x32_bf16(afl[mi], bfh[ni], acc[mi][ni], 0, 0, 0);
        acc[mi][ni] = __builtin_amdgcn_mfma_f32_16x16x32_bf16(afh[mi], bfl[ni], acc[mi][ni], 0, 0, 0);
      }
    __syncthreads();
  }
  #pragma unroll
  for (int mi=0;mi<4;mi++)
    #pragma unroll
    for (int ni=0;ni<4;ni++){
      int col  = n0 + wn*64 + ni*16 + (lane & 15);
      int row0 = m0 + wm*64 + mi*16 + (lane >> 4)*4;
      #pragma unroll
      for (int rr=0;rr<4;rr++)
        C[(size_t)(row0+rr)*N + col] = (_Float16)acc[mi][ni][rr];
    }
}

// ---------------------------------------------------------------------------
// Grid barrier WITHOUT __threadfence: all cross-block data uses agent-scope
// (sc1, LLC-coherent) atomics, so no L2 writeback/invalidate is needed.
// Release = s_waitcnt vmcnt(0) before arrival; acquire = sc1 reads after.
// ---------------------------------------------------------------------------
__device__ __forceinline__ void grid_barrier(unsigned* cnt, unsigned* epoch, unsigned target){
  asm volatile("s_waitcnt vmcnt(0)" ::: "memory");
  __syncthreads();
  if (threadIdx.x == 0){
    unsigned pos = __hip_atomic_fetch_add(cnt, 1u, __ATOMIC_RELAXED, __HIP_MEMORY_SCOPE_AGENT);
    if (pos == gridDim.x - 1u){
      __hip_atomic_store(cnt, 0u, __ATOMIC_RELAXED, __HIP_MEMORY_SCOPE_AGENT);
      asm volatile("s_waitcnt vmcnt(0)" ::: "memory");   // reset visible before publish
      __hip_atomic_fetch_add(epoch, 1u, __ATOMIC_RELAXED, __HIP_MEMORY_SCOPE_AGENT);
    } else {
      while (__hip_atomic_load(epoch, __ATOMIC_RELAXED, __HIP_MEMORY_SCOPE_AGENT) < target)
        __builtin_amdgcn_s_sleep(2);
    }
  }
  __syncthreads();
}

// ---------------------------------------------------------------------------
// LSTM layer. Weights/xp: plain (cached) loads — read-only, stay L1/L2-hot.
// h/pre/pg: agent-scope sc1 accesses (LLC-coherent). h gathered to LDS per step.
// ---------------------------------------------------------------------------
__global__ __launch_bounds__(512) void lstm_layer(
    const _Float16* __restrict__ xp,         // [16384][4096] fp16
    const float* __restrict__ whh,           // [2][2048][512]
    const float* __restrict__ gg, const float* __restrict__ gb,
    const float* __restrict__ cgam, const float* __restrict__ cbet,
    float* __restrict__ h_buf,               // [2][32][512]
    float* __restrict__ pre_buf,             // [2][32][2048]
    float* __restrict__ pg,                  // [2][32][4][2][128]
    unsigned* __restrict__ bar,
    float* __restrict__ out)                 // [16384][1024]
{
  int wg = blockIdx.x;
  int dir = wg >> 7, slice = wg & 127;
  int tid = threadIdx.x;
  int b = tid >> 4, idx = tid & 15, g = idx >> 2, jj = idx & 3;
  int j = slice*4 + jj, col = g*512 + j;
  const float* wrow = whh + ((size_t)dir*2048 + col)*512;
  int dirB = wg >> 5, bB = wg & 31;

  __shared__ float h_lds[32][516];           // +4 pad: avoid 4-way bank conflict
  __shared__ float c_lds[512];
  __shared__ float redg[16];
  __shared__ float redc[16];
  __shared__ float prestat[4][2];
  __shared__ float cst[2];
  if (wg < 64) c_lds[tid] = 0.0f;
  const float* hbase = h_buf + dir*16384;

  unsigned bar_t = 0;

  for (int t = 0; t < 512; ++t){
    int pos = dir ? (511 - t) : t;
    // -------- gather h (LLC) -> LDS --------
    for (int i = tid; i < 16384; i += 512)
      h_lds[i >> 9][i & 511] = agent_load(hbase + i);
    __syncthreads();
    // -------- phase A: pre-activation slice + partial LN stats --------
    float acc = (float)xp[(size_t)(pos*32 + b)*4096 + dir*2048 + col];
    #pragma unroll 8
    for (int k = 0; k < 512; k += 4){
      f32x4 hv = *(const f32x4*)&h_lds[b][k];
      f32x4 wv = *(const f32x4*)(wrow + k);
      acc += hv[0]*wv[0] + hv[1]*wv[1] + hv[2]*wv[2] + hv[3]*wv[3];
    }
    agent_store(pre_buf + (size_t)(dir*32 + b)*2048 + col, acc);
    float s = acc, q = acc*acc;
    s += __shfl_xor(s,1); q += __shfl_xor(q,1);
    s += __shfl_xor(s,2); q += __shfl_xor(q,2);
    if (jj == 0){
      float* base = pg + (size_t)(((dir*32 + b)*4 + g)*2)*128 + slice;
      agent_store(base, s); agent_store(base + 128, q);
    }
    grid_barrier(bar, bar+1, ++bar_t);
    // -------- phase B (blocks 0..63): LN + gates + cell + h --------
    if (wg < 64){
      int wv = tid >> 6, ln = tid & 63;
      {
        const float* src = pg + (size_t)(((dirB*32 + bB)*4 + (wv>>1))*2 + (wv&1))*128;
        float v = agent_load(src + ln) + agent_load(src + ln + 64);
        #pragma unroll
        for (int o=1;o<64;o<<=1) v += __shfl_xor(v,o);
        if (ln == 0) redg[wv] = v;
      }
      __syncthreads();
      if (tid < 4){
        float ssum = redg[tid*2], sq = redg[tid*2+1];
        float mean = ssum*(1.0f/512.0f);
        float var  = sq*(1.0f/512.0f) - mean*mean;
        prestat[tid][0] = mean; prestat[tid][1] = rsqrtf(var + LN_EPS);
      }
      __syncthreads();
      int jB = tid;
      const float* prow = pre_buf + (size_t)(dirB*32 + bB)*2048;
      int gbase = dirB*2048;
      float pi = (agent_load(prow+jB)      - prestat[0][0])*prestat[0][1]*gg[gbase+jB]      + gb[gbase+jB];
      float pf = (agent_load(prow+512+jB)  - prestat[1][0])*prestat[1][1]*gg[gbase+512+jB]  + gb[gbase+512+jB];
      float pv = (agent_load(prow+1024+jB) - prestat[2][0])*prestat[2][1]*gg[gbase+1024+jB] + gb[gbase+1024+jB];
      float po = (agent_load(prow+1536+jB) - prestat[3][0])*prestat[3][1]*gg[gbase+1536+jB] + gb[gbase+1536+jB];
      float cn = sigmoidf_(pf)*c_lds[jB] + sigmoidf_(pi)*tanhf(pv);
      c_lds[jB] = cn;
      float cs = cn, cq = cn*cn;
      #pragma unroll
      for (int o=1;o<64;o<<=1){ cs += __shfl_xor(cs,o); cq += __shfl_xor(cq,o); }
      if (ln == 0){ redc[wv*2] = cs; redc[wv*2+1] = cq; }
      __syncthreads();
      if (tid == 0){
        float S=0,Q=0;
        #pragma unroll
        for (int i=0;i<8;i++){ S += redc[i*2]; Q += redc[i*2+1]; }
        float m = S*(1.0f/512.0f);
        float v = Q*(1.0f/512.0f) - m*m;
        cst[0] = m; cst[1] = rsqrtf(v + LN_EPS);
      }
      __syncthreads();
      float cl = (cn - cst[0])*cst[1]*cgam[dirB*512+jB] + cbet[dirB*512+jB];
      float hv = sigmoidf_(po) * tanhf(cl);
      agent_store(h_buf + (dirB*32 + bB)*512 + jB, hv);
      int posB = dirB ? (511 - t) : t;
      out[(size_t)(posB*32 + bB)*1024 + dirB*512 + jB] = hv;   // plain: inter-kernel
    }
    grid_barrier(bar, bar+1, ++bar_t);
  }
}

// ---------------------------------------------------------------------------
__global__ void k_bn2_stats(const float* __restrict__ h1, float* __restrict__ stats){
  int tid = threadIdx.x;
  int c4 = tid*4;
  float s[4]={0,0,0,0}, q[4]={0,0,0,0};
  int rbase = blockIdx.x*64;
  for (int i=0;i<64;i++){
    f32x4 v = *(const f32x4*)(h1 + (size_t)(rbase+i)*1024 + c4);
    #pragma unroll
    for (int e=0;e<4;e++){ s[e]+=v[e]; q[e]+=v[e]*v[e]; }
  }
  #pragma unroll
  for (int e=0;e<4;e++){
    atomicAdd(&stats[c4+e], s[e]);
    atomicAdd(&stats[1024+c4+e], q[e]);
  }
}

__global__ void k_bn2_fin(const float* __restrict__ stats, const float* __restrict__ gamma,
                          const float* __restrict__ beta, float* __restrict__ ss){
  int c = blockIdx.x*256 + threadIdx.x;
  if (c < 1024){
    float N = 16384.0f;
    float mean = stats[c]/N;
    float var  = stats[1024+c]/N - mean*mean;
    float scale = gamma[c] * rsqrtf(var + LN_EPS);
    ss[c] = scale;
    ss[1024+c] = beta[c] - mean*scale;
  }
}

__global__ void k_att1(const float* __restrict__ h1, const float* __restrict__ ss,
                       const float* __restrict__ wom, const float* __restrict__ bom,
                       const float* __restrict__ uom, float* __restrict__ vu){
  __shared__ float tmp[4][64];
  int tid = threadIdx.x, wave = tid >> 6, ln = tid & 63;
  int part = ln/20, a = ln - part*20;
  bool active = (part < 3);
  for (int rr = 0; rr < 4; ++rr){
    int row = blockIdx.x*16 + wave*4 + rr;
    float acc = 0.0f;
    if (active){
      int n0 = part*342, n1 = (part==2) ? 1024 : (n0+342);
      for (int n = n0; n < n1; ++n){
        float hv = h1[(size_t)row*1024 + n]*ss[n] + ss[1024+n];
        acc += hv * wom[n*20 + a];
      }
    }
    tmp[wave][ln] = acc;
    __syncthreads();
    float pv = 0.0f;
    if (ln < 20){
      float v = tanhf(tmp[wave][ln] + tmp[wave][ln+20] + tmp[wave][ln+40] + bom[ln]);
      pv = v*uom[ln];
    }
    #pragma unroll
    for (int o=1;o<32;o<<=1) pv += __shfl_xor(pv, o);
    if (ln == 0) vu[row] = pv;
    __syncthreads();
  }
}

__global__ void k_att3(const float* __restrict__ h1, const float* __restrict__ ss,
                       const float* __restrict__ vu, float* __restrict__ out){
  __shared__ float al[512];
  __shared__ float red[4];
  int tid = threadIdx.x;
  int b = blockIdx.x >> 3, ch = blockIdx.x & 7;
  for (int t = tid; t < 512; t += 128) al[t] = vu[t*32 + b];
  __syncthreads();
  float m = -1e30f;
  for (int t = tid; t < 512; t += 128) m = fmaxf(m, al[t]);
  #pragma unroll
  for (int o=1;o<64;o<<=1) m = fmaxf(m, __shfl_xor(m,o));
  if ((tid & 63) == 0) red[tid>>6] = m;
  __syncthreads();
  m = fmaxf(red[0], red[1]);
  float s = 0.0f;
  for (int t = tid; t < 512; t += 128){ float e = expf(al[t]-m); al[t] = e; s += e; }
  #pragma unroll
  for (int o=1;o<64;o<<=1) s += __shfl_xor(s,o);
  if ((tid & 63) == 0) red[2 + (tid>>6)] = s;
  __syncthreads();
  float inv = 1.0f / (red[2] + red[3]);
  int n = ch*128 + tid;
  float acc = 0.0f;
  #pragma unroll 4
  for (int t = 0; t < 512; ++t) acc += al[t]*h1[(size_t)(t*32+b)*1024 + n];
  out[b*1024 + n] = acc*inv*ss[n] + ss[1024+n];
}

// ---------------------------------------------------------------------------
extern "C" void kernel_launch(void* const* d_in, const int* in_sizes, int n_in,
                              void* d_out, int out_size, void* d_ws, size_t ws_size,
                              hipStream_t stream){
  const float* x    = (const float*)d_in[0];
  const float* bn1g = (const float*)d_in[1];
  const float* bn1b = (const float*)d_in[2];
  const float* bn2g = (const float*)d_in[3];
  const float* bn2b = (const float*)d_in[4];
  const float* wih0 = (const float*)d_in[5];
  const float* whh0 = (const float*)d_in[6];
  const float* gg0  = (const float*)d_in[7];
  const float* gb0  = (const float*)d_in[8];
  const float* cg0  = (const float*)d_in[9];
  const float* cb0  = (const float*)d_in[10];
  const float* wih1 = (const float*)d_in[11];
  const float* whh1 = (const float*)d_in[12];
  const float* gg1  = (const float*)d_in[13];
  const float* gb1  = (const float*)d_in[14];
  const float* cg1  = (const float*)d_in[15];
  const float* cb1  = (const float*)d_in[16];
  const float* wom  = (const float*)d_in[17];
  const float* bom  = (const float*)d_in[18];
  const float* uom  = (const float*)d_in[19];
  float* out = (float*)d_out;

  char* w = (char*)d_ws;
  size_t off = 0;
  auto take = [&](size_t bytes)->void*{
    void* p = w + off;
    off += (bytes + 255) & ~(size_t)255;
    return p;
  };
  _Float16* xp = (_Float16*)take(16384ull*4096*2);      // 128 MB (both layers)
  float* hA = (float*)take(16384ull*1024*4);            // 64 MB (h0, then h1)
  __hip_bfloat16* w0hi = (__hip_bfloat16*)take(4096ull*128*2);
  __hip_bfloat16* w0lo = (__hip_bfloat16*)take(4096ull*128*2);
  __hip_bfloat16* w1hi = (__hip_bfloat16*)take(4096ull*1024*2);
  __hip_bfloat16* w1lo = (__hip_bfloat16*)take(4096ull*1024*2);
  float* hbuf   = (float*)take(2ull*32*512*4);
  unsigned* bar = (unsigned*)take(256);
  float* prebuf = (float*)take(2ull*32*2048*4);
  float* pgbuf  = (float*)take(2ull*32*4*2*128*4);
  float* stats1 = (float*)take(256*4);
  float* ss1    = (float*)take(256*4);
  float* stats2 = (float*)take(2048*4);
  float* ss2    = (float*)take(2048*4);
  float* vu     = (float*)take(16384ull*4);
  (void)ws_size; (void)in_sizes; (void)n_in; (void)out_size;

  hipMemsetAsync(stats1, 0, 256*4, stream);
  hipMemsetAsync(stats2, 0, 2048*4, stream);

  k_bn1_stats<<<256,256,0,stream>>>(x, stats1);
  k_bn1_fin<<<1,128,0,stream>>>(stats1, bn1g, bn1b, ss1);
  k_cvt_split<<<256,256,0,stream>>>(wih0, w0hi, w0lo, 4096*128);
  k_cvt_split<<<2048,256,0,stream>>>(wih1, w1hi, w1lo, 4096*1024);

  // GEMM0: xp = bn1(x) @ w_ih0^T
  gemm_split<<<dim3(32,128),256,0,stream>>>(x, w0hi, w0lo, xp, 16384, 4096, 128, 1, ss1);

  // ---- layer 0 ----
  hipMemsetAsync(hbuf, 0, 2*32*512*4 + 256, stream);
  {
    const _Float16* xp_c = xp;
    const float *whh = whh0, *gg = gg0, *gb = gb0, *cgam = cg0, *cbet = cb0;
    float* o = hA;
    void* args[] = {(void*)&xp_c,(void*)&whh,(void*)&gg,(void*)&gb,(void*)&cgam,(void*)&cbet,
                    (void*)&hbuf,(void*)&prebuf,(void*)&pgbuf,(void*)&bar,(void*)&o};
    hipLaunchCooperativeKernel((const void*)lstm_layer, dim3(256), dim3(512), args, 0, stream);
  }

  // GEMM1: xp = h0 @ w_ih1^T
  gemm_split<<<dim3(32,128),256,0,stream>>>(hA, w1hi, w1lo, xp, 16384, 4096, 1024, 0, nullptr);

  // ---- layer 1 ----
  hipMemsetAsync(hbuf, 0, 2*32*512*4 + 256, stream);
  {
    const _Float16* xp_c = xp;
    const float *whh = whh1, *gg = gg1, *gb = gb1, *cgam = cg1, *cbet = cb1;
    float* o = hA;
    void* args[] = {(void*)&xp_c,(void*)&whh,(void*)&gg,(void*)&gb,(void*)&cgam,(void*)&cbet,
                    (void*)&hbuf,(void*)&prebuf,(void*)&pgbuf,(void*)&bar,(void*)&o};
    hipLaunchCooperativeKernel((const void*)lstm_layer, dim3(256), dim3(512), args, 0, stream);
  }

  k_bn2_stats<<<256,256,0,stream>>>(hA, stats2);
  k_bn2_fin<<<4,256,0,stream>>>(stats2, bn2g, bn2b, ss2);
  k_att1<<<1024,256,0,stream>>>(hA, ss2, wom, bom, uom, vu);
  k_att3<<<256,128,0,stream>>>(hA, ss2, vu, out);
}

// Round 6
// 15383.751 us; speedup vs baseline: 5.3177x; 3.5072x over previous
//
#include <hip/hip_runtime.h>
#include <hip/hip_bf16.h>

#define LN_EPS 1e-5f

typedef __attribute__((ext_vector_type(4))) float    f32x4;
typedef __attribute__((ext_vector_type(8))) short    s16x8;
typedef __attribute__((ext_vector_type(8))) _Float16 f16x8;
typedef __attribute__((ext_vector_type(4))) unsigned u32x4;

__device__ __forceinline__ float sigmoidf_(float x){ return 1.0f/(1.0f+expf(-x)); }

__device__ __forceinline__ short bf16_hi_bits(float f){
  __hip_bfloat16 h = __float2bfloat16(f);
  return *reinterpret_cast<short*>(&h);
}
__device__ __forceinline__ float bf16_hi_val(float f){
  return __bfloat162float(__float2bfloat16(f));
}

__device__ __forceinline__ unsigned agent_load_u(const unsigned* p){
  return __hip_atomic_load((unsigned*)p, __ATOMIC_RELAXED, __HIP_MEMORY_SCOPE_AGENT);
}
__device__ __forceinline__ void agent_store_u(unsigned* p, unsigned v){
  __hip_atomic_store(p, v, __ATOMIC_RELAXED, __HIP_MEMORY_SCOPE_AGENT);
}

// ---------------------------------------------------------------------------
// bn1
// ---------------------------------------------------------------------------
__global__ void k_bn1_stats(const float* __restrict__ x, float* __restrict__ stats){
  int tid = threadIdx.x;
  int cg = tid >> 3, ro = tid & 7;
  int c4 = cg * 4;
  float s[4] = {0,0,0,0}, q[4] = {0,0,0,0};
  int rbase = blockIdx.x * 64;
  for (int i = 0; i < 8; ++i){
    int row = rbase + i*8 + ro;
    f32x4 v = *(const f32x4*)(x + (size_t)row*128 + c4);
    #pragma unroll
    for (int e=0;e<4;e++){ s[e]+=v[e]; q[e]+=v[e]*v[e]; }
  }
  #pragma unroll
  for (int o=1;o<8;o<<=1){
    #pragma unroll
    for (int e=0;e<4;e++){ s[e]+=__shfl_xor(s[e],o); q[e]+=__shfl_xor(q[e],o); }
  }
  if (ro==0){
    #pragma unroll
    for (int e=0;e<4;e++){
      atomicAdd(&stats[c4+e], s[e]);
      atomicAdd(&stats[128+c4+e], q[e]);
    }
  }
}

__global__ void k_bn1_fin(const float* __restrict__ stats, const float* __restrict__ gamma,
                          const float* __restrict__ beta, float* __restrict__ ss){
  int c = threadIdx.x;
  if (c < 128){
    float N = 16384.0f;
    float mean = stats[c]/N;
    float var  = stats[128+c]/N - mean*mean;
    float scale = gamma[c] * rsqrtf(var + LN_EPS);
    ss[c] = scale;
    ss[128+c] = beta[c] - mean*scale;
  }
}

// split f32 -> (hi, lo) bf16 pair
__global__ void k_cvt_split(const float* __restrict__ s, __hip_bfloat16* __restrict__ hi,
                            __hip_bfloat16* __restrict__ lo, int n){
  for (int i = blockIdx.x*blockDim.x + threadIdx.x; i < n; i += gridDim.x*blockDim.x){
    float v = s[i];
    __hip_bfloat16 h = __float2bfloat16(v);
    hi[i] = h;
    lo[i] = __float2bfloat16(v - __bfloat162float(h));
  }
}

// pack whh [2][2048][512] f32 -> fragment-linear f16
// wpk[(dir*4+gate)][kt=16][c16=32][lane=64][8]
__global__ void k_pack_whh(const float* __restrict__ whh, _Float16* __restrict__ wpk){
  size_t i = (size_t)blockIdx.x*256 + threadIdx.x;     // over 2*2048*512
  int k = (int)(i & 511);
  size_t ci = i >> 9;
  int col = (int)(ci & 2047);
  int dirr = (int)(ci >> 11);
  int gate = col >> 9, cig = col & 511, c16 = cig >> 4, lc = cig & 15;
  int kt = k >> 5, ksub = k & 31, hi = ksub >> 3, j = ksub & 7;
  size_t dst = ((((size_t)(dirr*4+gate)*16 + kt)*32 + c16)*64 + (hi*16+lc))*8 + j;
  wpk[dst] = (_Float16)whh[i];
}

// ---------------------------------------------------------------------------
// Split-bf16 fp32-accurate GEMM: C[M][N] = A[M][K] * B[N][K]^T, C fp16.
// ---------------------------------------------------------------------------
__global__ __launch_bounds__(256) void gemm_split(const float* __restrict__ A,
                                                  const __hip_bfloat16* __restrict__ Bhi,
                                                  const __hip_bfloat16* __restrict__ Blo,
                                                  _Float16* __restrict__ C,
                                                  int M, int N, int K,
                                                  int a_mode, const float* __restrict__ ss){
  __shared__ __align__(16) __hip_bfloat16 Ah[128*32];
  __shared__ __align__(16) __hip_bfloat16 Al[128*32];
  __shared__ __align__(16) __hip_bfloat16 Bh[128*32];
  __shared__ __align__(16) __hip_bfloat16 Bl[128*32];
  int n0 = blockIdx.x * 128, m0 = blockIdx.y * 128;
  int tid = threadIdx.x, lane = tid & 63, wave = tid >> 6;
  int wm = wave >> 1, wn = wave & 1;
  f32x4 acc[4][4] = {};
  int r = tid >> 2, sseg = tid & 3;
  for (int kt = 0; kt < K; kt += 32){
    #pragma unroll
    for (int half = 0; half < 2; ++half){
      int m = m0 + half*64 + r;
      const float* src;
      if (a_mode){
        int t = m >> 5, b = m & 31;
        src = A + ((size_t)(b*512 + t))*128 + kt + sseg*8;
      } else {
        src = A + (size_t)m*K + kt + sseg*8;
      }
      f32x4 v0 = *(const f32x4*)src;
      f32x4 v1 = *(const f32x4*)(src + 4);
      s16x8 vh, vl;
      #pragma unroll
      for (int e=0;e<4;e++){
        float f0 = v0[e], f1 = v1[e];
        if (a_mode){
          int k = kt + sseg*8;
          f0 = f0*ss[k+e]   + ss[128+k+e];
          f1 = f1*ss[k+4+e] + ss[128+k+4+e];
        }
        float h0 = bf16_hi_val(f0), h1 = bf16_hi_val(f1);
        vh[e]   = bf16_hi_bits(f0); vl[e]   = bf16_hi_bits(f0 - h0);
        vh[4+e] = bf16_hi_bits(f1); vl[4+e] = bf16_hi_bits(f1 - h1);
      }
      *(s16x8*)&Ah[(half*64+r)*32 + sseg*8] = vh;
      *(s16x8*)&Al[(half*64+r)*32 + sseg*8] = vl;
      u32x4 bh = *(const u32x4*)(Bhi + (size_t)(n0 + half*64 + r)*K + kt + sseg*8);
      u32x4 bl = *(const u32x4*)(Blo + (size_t)(n0 + half*64 + r)*K + kt + sseg*8);
      *(u32x4*)&Bh[(half*64+r)*32 + sseg*8] = bh;
      *(u32x4*)&Bl[(half*64+r)*32 + sseg*8] = bl;
    }
    __syncthreads();
    s16x8 afh[4], afl[4], bfh[4], bfl[4];
    int k8 = (lane >> 4) * 8;
    int ra = wm*64 + (lane & 15), rb = wn*64 + (lane & 15);
    #pragma unroll
    for (int mi=0;mi<4;mi++){
      afh[mi] = *(const s16x8*)&Ah[(ra + mi*16)*32 + k8];
      afl[mi] = *(const s16x8*)&Al[(ra + mi*16)*32 + k8];
    }
    #pragma unroll
    for (int ni=0;ni<4;ni++){
      bfh[ni] = *(const s16x8*)&Bh[(rb + ni*16)*32 + k8];
      bfl[ni] = *(const s16x8*)&Bl[(rb + ni*16)*32 + k8];
    }
    #pragma unroll
    for (int mi=0;mi<4;mi++)
      #pragma unroll
      for (int ni=0;ni<4;ni++){
        acc[mi][ni] = __builtin_amdgcn_mfma_f32_16x16x32_bf16(afh[mi], bfh[ni], acc[mi][ni], 0, 0, 0);
        acc[mi][ni] = __builtin_amdgcn_mfma_f32_16x16x32_bf16(afl[mi], bfh[ni], acc[mi][ni], 0, 0, 0);
        acc[mi][ni] = __builtin_amdgcn_mfma_f32_16x16x32_bf16(afh[mi], bfl[ni], acc[mi][ni], 0, 0, 0);
      }
    __syncthreads();
  }
  #pragma unroll
  for (int mi=0;mi<4;mi++)
    #pragma unroll
    for (int ni=0;ni<4;ni++){
      int col  = n0 + wn*64 + ni*16 + (lane & 15);
      int row0 = m0 + wm*64 + mi*16 + (lane >> 4)*4;
      #pragma unroll
      for (int rr=0;rr<4;rr++)
        C[(size_t)(row0+rr)*N + col] = (_Float16)acc[mi][ni][rr];
    }
}

// ---------------------------------------------------------------------------
// LSTM, barrier-free: 64 blocks = (bq 0..7) x (dir 0..1) x (gate 0..3).
// Block owns gate-slice GEMV for its 4 b's (M=16-pad MFMA f16), local gate-LN,
// publishes post-LN gate tile; 4 sibling gate-blocks exchange tiles via LLC
// flags; cell update replicated per sibling (h stays block-local in LDS).
// ---------------------------------------------------------------------------
__global__ __launch_bounds__(512) void lstm_fast(
    const _Float16* __restrict__ xp,     // [16384][4096]
    const _Float16* __restrict__ wpk,    // [8 slices][16][32][64][8]
    const float* __restrict__ gg, const float* __restrict__ gb,   // [2][2048]
    const float* __restrict__ cgam, const float* __restrict__ cbet, // [2][512]
    float* __restrict__ out,             // [16384][1024]
    _Float16* __restrict__ tiles,        // [64][2][4][512]
    unsigned* __restrict__ flags)        // [64*64]
{
  int blk = blockIdx.x;
  int slice = blk & 7;                 // (dir,gate) -> XCD via round-robin
  int dir = slice >> 2, gate = slice & 3, bq = blk >> 3;
  int tid = threadIdx.x, lane = tid & 63, wv = tid >> 6;
  int b0 = bq * 4;

  __shared__ __align__(16) _Float16 hfrag[16*64*8];   // 16KB  A-fragments
  __shared__ float    c_s[4][512];                    // 8KB
  __shared__ _Float16 tile_own[4][512];               // 4KB
  __shared__ _Float16 tile_sib[3][4][512];            // 12KB
  __shared__ float    red[8][4][2];
  __shared__ float    stat[4][2];
  __shared__ float    redc[8][4][2];
  __shared__ float    cstat[4][2];

  for (int i = tid; i < 16*64*8; i += 512) hfrag[i] = (_Float16)0.f;
  for (int i = tid; i < 4*512;  i += 512) c_s[i>>9][i&511] = 0.f;
  __syncthreads();

  const _Float16* wbase = wpk + (size_t)slice * (16*32*64*8);
  int sib[3];
  #pragma unroll
  for (int s = 0; s < 3; ++s){
    int g2 = s + (s >= gate ? 1 : 0);
    sib[s] = (bq << 3) | (dir << 2) | g2;
  }
  int c16base = wv * 4;

  for (int t = 0; t < 512; ++t){
    int pos = dir ? (511 - t) : t;
    // ---- GEMV: pre[16pad][512cols of gate] = hfrag x w ----
    f32x4 acc[4] = {};
    #pragma unroll 4
    for (int kt = 0; kt < 16; ++kt){
      f16x8 afrag = *(const f16x8*)&hfrag[(kt*64 + lane)*8];
      #pragma unroll
      for (int ct = 0; ct < 4; ++ct){
        f16x8 bfrag = *(const f16x8*)&wbase[(((size_t)kt*32 + c16base + ct)*64 + lane)*8];
        acc[ct] = __builtin_amdgcn_mfma_f32_16x16x32_f16(afrag, bfrag, acc[ct], 0, 0, 0);
      }
    }
    // ---- add xp, LN partials (lanes 0..15 hold rows b=0..3 in regs 0..3) ----
    float s[4] = {0,0,0,0}, q[4] = {0,0,0,0};
    if ((lane >> 4) == 0){
      #pragma unroll
      for (int ct = 0; ct < 4; ++ct){
        int col = gate*512 + (c16base + ct)*16 + lane;
        #pragma unroll
        for (int r = 0; r < 4; ++r){
          float v = acc[ct][r] +
            (float)xp[(size_t)(pos*32 + b0 + r)*4096 + dir*2048 + col];
          acc[ct][r] = v; s[r] += v; q[r] += v*v;
        }
      }
    }
    #pragma unroll
    for (int o = 1; o < 16; o <<= 1){
      #pragma unroll
      for (int r = 0; r < 4; ++r){ s[r] += __shfl_xor(s[r], o); q[r] += __shfl_xor(q[r], o); }
    }
    if (lane == 0){
      #pragma unroll
      for (int r = 0; r < 4; ++r){ red[wv][r][0] = s[r]; red[wv][r][1] = q[r]; }
    }
    __syncthreads();
    if (tid < 4){
      float S = 0.f, Q = 0.f;
      #pragma unroll
      for (int w = 0; w < 8; ++w){ S += red[w][tid][0]; Q += red[w][tid][1]; }
      float mean = S*(1.0f/512.0f);
      float var  = Q*(1.0f/512.0f) - mean*mean;
      stat[tid][0] = mean; stat[tid][1] = rsqrtf(var + LN_EPS);
    }
    __syncthreads();
    // ---- post-LN -> tile_own ----
    if ((lane >> 4) == 0){
      #pragma unroll
      for (int ct = 0; ct < 4; ++ct){
        int cig = (c16base + ct)*16 + lane;
        int gi = dir*2048 + gate*512 + cig;
        #pragma unroll
        for (int r = 0; r < 4; ++r){
          float v = (acc[ct][r] - stat[r][0])*stat[r][1]*gg[gi] + gb[gi];
          tile_own[r][cig] = (_Float16)v;
        }
      }
    }
    __syncthreads();
    // ---- publish own tile + flag ----
    {
      int buf = t & 1;
      unsigned* dst = (unsigned*)(tiles + ((size_t)blk*2 + buf)*2048);
      const unsigned* srcu = (const unsigned*)&tile_own[0][0];
      for (int i = tid; i < 1024; i += 512) agent_store_u(dst + i, srcu[i]);
      asm volatile("s_waitcnt vmcnt(0)" ::: "memory");
      __syncthreads();
      if (tid == 0)
        __hip_atomic_store(&flags[blk*64], (unsigned)(t+1), __ATOMIC_RELAXED, __HIP_MEMORY_SCOPE_AGENT);
      // ---- wait siblings, read their tiles ----
      if (tid < 3){
        while (__hip_atomic_load(&flags[sib[tid]*64], __ATOMIC_RELAXED, __HIP_MEMORY_SCOPE_AGENT)
               < (unsigned)(t+1))
          __builtin_amdgcn_s_sleep(1);
      }
      __syncthreads();
      #pragma unroll
      for (int sb = 0; sb < 3; ++sb){
        const unsigned* src = (const unsigned*)(tiles + ((size_t)sib[sb]*2 + buf)*2048);
        unsigned* d = (unsigned*)&tile_sib[sb][0][0];
        for (int i = tid; i < 1024; i += 512) d[i] = agent_load_u(src + i);
      }
      __syncthreads();
    }
    // ---- cell update (replicated across the 4 sibling blocks) ----
    const _Float16* gp0 = (gate == 0) ? &tile_own[0][0] : &tile_sib[0 - (0 > gate ? 1 : 0)][0][0];
    const _Float16* gp1 = (gate == 1) ? &tile_own[0][0] : &tile_sib[1 - (1 > gate ? 1 : 0)][0][0];
    const _Float16* gp2 = (gate == 2) ? &tile_own[0][0] : &tile_sib[2 - (2 > gate ? 1 : 0)][0][0];
    const _Float16* gp3 = (gate == 3) ? &tile_own[0][0] : &tile_sib[3 - (3 > gate ? 1 : 0)][0][0];
    float cs[4], cq[4];
    #pragma unroll
    for (int b = 0; b < 4; ++b){
      float iv = (float)gp0[b*512 + tid];
      float fv = (float)gp1[b*512 + tid];
      float gv = (float)gp2[b*512 + tid];
      float cn = sigmoidf_(fv)*c_s[b][tid] + sigmoidf_(iv)*tanhf(gv);
      c_s[b][tid] = cn;
      cs[b] = cn; cq[b] = cn*cn;
    }
    #pragma unroll
    for (int o = 1; o < 64; o <<= 1){
      #pragma unroll
      for (int b = 0; b < 4; ++b){ cs[b] += __shfl_xor(cs[b], o); cq[b] += __shfl_xor(cq[b], o); }
    }
    if (lane == 0){
      #pragma unroll
      for (int b = 0; b < 4; ++b){ redc[wv][b][0] = cs[b]; redc[wv][b][1] = cq[b]; }
    }
    __syncthreads();
    if (tid < 4){
      float S = 0.f, Q = 0.f;
      #pragma unroll
      for (int w = 0; w < 8; ++w){ S += redc[w][tid][0]; Q += redc[w][tid][1]; }
      float mean = S*(1.0f/512.0f);
      float var  = Q*(1.0f/512.0f) - mean*mean;
      cstat[tid][0] = mean; cstat[tid][1] = rsqrtf(var + LN_EPS);
    }
    __syncthreads();
    float cgv = cgam[dir*512 + tid], cbv = cbet[dir*512 + tid];
    #pragma unroll
    for (int b = 0; b < 4; ++b){
      float cl = (c_s[b][tid] - cstat[b][0])*cstat[b][1]*cgv + cbv;
      float hv = sigmoidf_((float)gp3[b*512 + tid]) * tanhf(cl);
      // hfrag[(kt*64 + hi*16 + b)*8 + jj],  k = tid
      hfrag[(((tid >> 5)*64) + ((tid & 31) >> 3)*16 + b)*8 + (tid & 7)] = (_Float16)hv;
      if (gate == 0)
        out[(size_t)(pos*32 + b0 + b)*1024 + dir*512 + tid] = hv;
    }
    __syncthreads();
  }
}

// ---------------------------------------------------------------------------
__global__ void k_bn2_stats(const float* __restrict__ h1, float* __restrict__ stats){
  int tid = threadIdx.x;
  int c4 = tid*4;
  float s[4]={0,0,0,0}, q[4]={0,0,0,0};
  int rbase = blockIdx.x*64;
  for (int i=0;i<64;i++){
    f32x4 v = *(const f32x4*)(h1 + (size_t)(rbase+i)*1024 + c4);
    #pragma unroll
    for (int e=0;e<4;e++){ s[e]+=v[e]; q[e]+=v[e]*v[e]; }
  }
  #pragma unroll
  for (int e=0;e<4;e++){
    atomicAdd(&stats[c4+e], s[e]);
    atomicAdd(&stats[1024+c4+e], q[e]);
  }
}

__global__ void k_bn2_fin(const float* __restrict__ stats, const float* __restrict__ gamma,
                          const float* __restrict__ beta, float* __restrict__ ss){
  int c = blockIdx.x*256 + threadIdx.x;
  if (c < 1024){
    float N = 16384.0f;
    float mean = stats[c]/N;
    float var  = stats[1024+c]/N - mean*mean;
    float scale = gamma[c] * rsqrtf(var + LN_EPS);
    ss[c] = scale;
    ss[1024+c] = beta[c] - mean*scale;
  }
}

__global__ void k_att1(const float* __restrict__ h1, const float* __restrict__ ss,
                       const float* __restrict__ wom, const float* __restrict__ bom,
                       const float* __restrict__ uom, float* __restrict__ vu){
  __shared__ float tmp[4][64];
  int tid = threadIdx.x, wave = tid >> 6, ln = tid & 63;
  int part = ln/20, a = ln - part*20;
  bool active = (part < 3);
  for (int rr = 0; rr < 4; ++rr){
    int row = blockIdx.x*16 + wave*4 + rr;
    float acc = 0.0f;
    if (active){
      int n0 = part*342, n1 = (part==2) ? 1024 : (n0+342);
      for (int n = n0; n < n1; ++n){
        float hv = h1[(size_t)row*1024 + n]*ss[n] + ss[1024+n];
        acc += hv * wom[n*20 + a];
      }
    }
    tmp[wave][ln] = acc;
    __syncthreads();
    float pv = 0.0f;
    if (ln < 20){
      float v = tanhf(tmp[wave][ln] + tmp[wave][ln+20] + tmp[wave][ln+40] + bom[ln]);
      pv = v*uom[ln];
    }
    #pragma unroll
    for (int o=1;o<32;o<<=1) pv += __shfl_xor(pv, o);
    if (ln == 0) vu[row] = pv;
    __syncthreads();
  }
}

__global__ void k_att3(const float* __restrict__ h1, const float* __restrict__ ss,
                       const float* __restrict__ vu, float* __restrict__ out){
  __shared__ float al[512];
  __shared__ float red[4];
  int tid = threadIdx.x;
  int b = blockIdx.x >> 3, ch = blockIdx.x & 7;
  for (int t = tid; t < 512; t += 128) al[t] = vu[t*32 + b];
  __syncthreads();
  float m = -1e30f;
  for (int t = tid; t < 512; t += 128) m = fmaxf(m, al[t]);
  #pragma unroll
  for (int o=1;o<64;o<<=1) m = fmaxf(m, __shfl_xor(m,o));
  if ((tid & 63) == 0) red[tid>>6] = m;
  __syncthreads();
  m = fmaxf(red[0], red[1]);
  float s = 0.0f;
  for (int t = tid; t < 512; t += 128){ float e = expf(al[t]-m); al[t] = e; s += e; }
  #pragma unroll
  for (int o=1;o<64;o<<=1) s += __shfl_xor(s,o);
  if ((tid & 63) == 0) red[2 + (tid>>6)] = s;
  __syncthreads();
  float inv = 1.0f / (red[2] + red[3]);
  int n = ch*128 + tid;
  float acc = 0.0f;
  #pragma unroll 4
  for (int t = 0; t < 512; ++t) acc += al[t]*h1[(size_t)(t*32+b)*1024 + n];
  out[b*1024 + n] = acc*inv*ss[n] + ss[1024+n];
}

// ---------------------------------------------------------------------------
extern "C" void kernel_launch(void* const* d_in, const int* in_sizes, int n_in,
                              void* d_out, int out_size, void* d_ws, size_t ws_size,
                              hipStream_t stream){
  const float* x    = (const float*)d_in[0];
  const float* bn1g = (const float*)d_in[1];
  const float* bn1b = (const float*)d_in[2];
  const float* bn2g = (const float*)d_in[3];
  const float* bn2b = (const float*)d_in[4];
  const float* wih0 = (const float*)d_in[5];
  const float* whh0 = (const float*)d_in[6];
  const float* gg0  = (const float*)d_in[7];
  const float* gb0  = (const float*)d_in[8];
  const float* cg0  = (const float*)d_in[9];
  const float* cb0  = (const float*)d_in[10];
  const float* wih1 = (const float*)d_in[11];
  const float* whh1 = (const float*)d_in[12];
  const float* gg1  = (const float*)d_in[13];
  const float* gb1  = (const float*)d_in[14];
  const float* cg1  = (const float*)d_in[15];
  const float* cb1  = (const float*)d_in[16];
  const float* wom  = (const float*)d_in[17];
  const float* bom  = (const float*)d_in[18];
  const float* uom  = (const float*)d_in[19];
  float* out = (float*)d_out;

  char* w = (char*)d_ws;
  size_t off = 0;
  auto take = [&](size_t bytes)->void*{
    void* p = w + off;
    off += (bytes + 255) & ~(size_t)255;
    return p;
  };
  _Float16* xp = (_Float16*)take(16384ull*4096*2);      // 128 MB
  float* hA = (float*)take(16384ull*1024*4);            // 64 MB
  __hip_bfloat16* w0hi = (__hip_bfloat16*)take(4096ull*128*2);
  __hip_bfloat16* w0lo = (__hip_bfloat16*)take(4096ull*128*2);
  __hip_bfloat16* w1hi = (__hip_bfloat16*)take(4096ull*1024*2);
  __hip_bfloat16* w1lo = (__hip_bfloat16*)take(4096ull*1024*2);
  _Float16* wpk0 = (_Float16*)take(2ull*2048*512*2);    // 4 MB
  _Float16* wpk1 = (_Float16*)take(2ull*2048*512*2);    // 4 MB
  _Float16* tiles = (_Float16*)take(64ull*2*4*512*2);   // 512 KB
  unsigned* flags = (unsigned*)take(64ull*64*4);        // 16 KB
  float* stats1 = (float*)take(256*4);
  float* ss1    = (float*)take(256*4);
  float* stats2 = (float*)take(2048*4);
  float* ss2    = (float*)take(2048*4);
  float* vu     = (float*)take(16384ull*4);
  (void)ws_size; (void)in_sizes; (void)n_in; (void)out_size;

  hipMemsetAsync(stats1, 0, 256*4, stream);
  hipMemsetAsync(stats2, 0, 2048*4, stream);

  k_bn1_stats<<<256,256,0,stream>>>(x, stats1);
  k_bn1_fin<<<1,128,0,stream>>>(stats1, bn1g, bn1b, ss1);
  k_cvt_split<<<256,256,0,stream>>>(wih0, w0hi, w0lo, 4096*128);
  k_cvt_split<<<2048,256,0,stream>>>(wih1, w1hi, w1lo, 4096*1024);
  k_pack_whh<<<8192,256,0,stream>>>(whh0, wpk0);
  k_pack_whh<<<8192,256,0,stream>>>(whh1, wpk1);

  // GEMM0: xp = bn1(x) @ w_ih0^T
  gemm_split<<<dim3(32,128),256,0,stream>>>(x, w0hi, w0lo, xp, 16384, 4096, 128, 1, ss1);

  // ---- layer 0 ----
  hipMemsetAsync(flags, 0, 64*64*4, stream);
  lstm_fast<<<64,512,0,stream>>>(xp, wpk0, gg0, gb0, cg0, cb0, hA, tiles, flags);

  // GEMM1: xp = h0 @ w_ih1^T
  gemm_split<<<dim3(32,128),256,0,stream>>>(hA, w1hi, w1lo, xp, 16384, 4096, 1024, 0, nullptr);

  // ---- layer 1 ----
  hipMemsetAsync(flags, 0, 64*64*4, stream);
  lstm_fast<<<64,512,0,stream>>>(xp, wpk1, gg1, gb1, cg1, cb1, hA, tiles, flags);

  k_bn2_stats<<<256,256,0,stream>>>(hA, stats2);
  k_bn2_fin<<<4,256,0,stream>>>(stats2, bn2g, bn2b, ss2);
  k_att1<<<1024,256,0,stream>>>(hA, ss2, wom, bom, uom, vu);
  k_att3<<<256,128,0,stream>>>(hA, ss2, vu, out);
}

// Round 7
// 8546.705 us; speedup vs baseline: 9.5716x; 1.8000x over previous
//
#include <hip/hip_runtime.h>
#include <hip/hip_bf16.h>

#define LN_EPS 1e-5f

typedef __attribute__((ext_vector_type(4))) float    f32x4;
typedef __attribute__((ext_vector_type(8))) short    s16x8;
typedef __attribute__((ext_vector_type(8))) _Float16 f16x8;
typedef __attribute__((ext_vector_type(4))) unsigned u32x4;

__device__ __forceinline__ float sigmoidf_(float x){ return 1.0f/(1.0f+expf(-x)); }

__device__ __forceinline__ short bf16_hi_bits(float f){
  __hip_bfloat16 h = __float2bfloat16(f);
  return *reinterpret_cast<short*>(&h);
}
__device__ __forceinline__ float bf16_hi_val(float f){
  return __bfloat162float(__float2bfloat16(f));
}

__device__ __forceinline__ float agent_load_f(const float* p){
  return __hip_atomic_load((float*)p, __ATOMIC_RELAXED, __HIP_MEMORY_SCOPE_AGENT);
}
__device__ __forceinline__ void agent_store_f(float* p, float v){
  __hip_atomic_store(p, v, __ATOMIC_RELAXED, __HIP_MEMORY_SCOPE_AGENT);
}

// ---------------------------------------------------------------------------
// bn1
// ---------------------------------------------------------------------------
__global__ void k_bn1_stats(const float* __restrict__ x, float* __restrict__ stats){
  int tid = threadIdx.x;
  int cg = tid >> 3, ro = tid & 7;
  int c4 = cg * 4;
  float s[4] = {0,0,0,0}, q[4] = {0,0,0,0};
  int rbase = blockIdx.x * 64;
  for (int i = 0; i < 8; ++i){
    int row = rbase + i*8 + ro;
    f32x4 v = *(const f32x4*)(x + (size_t)row*128 + c4);
    #pragma unroll
    for (int e=0;e<4;e++){ s[e]+=v[e]; q[e]+=v[e]*v[e]; }
  }
  #pragma unroll
  for (int o=1;o<8;o<<=1){
    #pragma unroll
    for (int e=0;e<4;e++){ s[e]+=__shfl_xor(s[e],o); q[e]+=__shfl_xor(q[e],o); }
  }
  if (ro==0){
    #pragma unroll
    for (int e=0;e<4;e++){
      atomicAdd(&stats[c4+e], s[e]);
      atomicAdd(&stats[128+c4+e], q[e]);
    }
  }
}

__global__ void k_bn1_fin(const float* __restrict__ stats, const float* __restrict__ gamma,
                          const float* __restrict__ beta, float* __restrict__ ss){
  int c = threadIdx.x;
  if (c < 128){
    float N = 16384.0f;
    float mean = stats[c]/N;
    float var  = stats[128+c]/N - mean*mean;
    float scale = gamma[c] * rsqrtf(var + LN_EPS);
    ss[c] = scale;
    ss[128+c] = beta[c] - mean*scale;
  }
}

// split f32 -> (hi, lo) bf16 pair
__global__ void k_cvt_split(const float* __restrict__ s, __hip_bfloat16* __restrict__ hi,
                            __hip_bfloat16* __restrict__ lo, int n){
  for (int i = blockIdx.x*blockDim.x + threadIdx.x; i < n; i += gridDim.x*blockDim.x){
    float v = s[i];
    __hip_bfloat16 h = __float2bfloat16(v);
    hi[i] = h;
    lo[i] = __float2bfloat16(v - __bfloat162float(h));
  }
}

// pack whh [2][2048][512] f32 -> fragment-linear f16
// wpk[(dir*4+gate)][kt=16][c16=32][lane=64][8]
__global__ void k_pack_whh(const float* __restrict__ whh, _Float16* __restrict__ wpk){
  size_t i = (size_t)blockIdx.x*256 + threadIdx.x;     // over 2*2048*512
  int k = (int)(i & 511);
  size_t ci = i >> 9;
  int col = (int)(ci & 2047);
  int dirr = (int)(ci >> 11);
  int gate = col >> 9, cig = col & 511, c16 = cig >> 4, lc = cig & 15;
  int kt = k >> 5, ksub = k & 31, hi = ksub >> 3, j = ksub & 7;
  size_t dst = ((((size_t)(dirr*4+gate)*16 + kt)*32 + c16)*64 + (hi*16+lc))*8 + j;
  wpk[dst] = (_Float16)whh[i];
}

// ---------------------------------------------------------------------------
// Split-bf16 fp32-accurate GEMM: C[M][N] = A[M][K] * B[N][K]^T, C fp16.
// ---------------------------------------------------------------------------
__global__ __launch_bounds__(256) void gemm_split(const float* __restrict__ A,
                                                  const __hip_bfloat16* __restrict__ Bhi,
                                                  const __hip_bfloat16* __restrict__ Blo,
                                                  _Float16* __restrict__ C,
                                                  int M, int N, int K,
                                                  int a_mode, const float* __restrict__ ss){
  __shared__ __align__(16) __hip_bfloat16 Ah[128*32];
  __shared__ __align__(16) __hip_bfloat16 Al[128*32];
  __shared__ __align__(16) __hip_bfloat16 Bh[128*32];
  __shared__ __align__(16) __hip_bfloat16 Bl[128*32];
  int n0 = blockIdx.x * 128, m0 = blockIdx.y * 128;
  int tid = threadIdx.x, lane = tid & 63, wave = tid >> 6;
  int wm = wave >> 1, wn = wave & 1;
  f32x4 acc[4][4] = {};
  int r = tid >> 2, sseg = tid & 3;
  for (int kt = 0; kt < K; kt += 32){
    #pragma unroll
    for (int half = 0; half < 2; ++half){
      int m = m0 + half*64 + r;
      const float* src;
      if (a_mode){
        int t = m >> 5, b = m & 31;
        src = A + ((size_t)(b*512 + t))*128 + kt + sseg*8;
      } else {
        src = A + (size_t)m*K + kt + sseg*8;
      }
      f32x4 v0 = *(const f32x4*)src;
      f32x4 v1 = *(const f32x4*)(src + 4);
      s16x8 vh, vl;
      #pragma unroll
      for (int e=0;e<4;e++){
        float f0 = v0[e], f1 = v1[e];
        if (a_mode){
          int k = kt + sseg*8;
          f0 = f0*ss[k+e]   + ss[128+k+e];
          f1 = f1*ss[k+4+e] + ss[128+k+4+e];
        }
        float h0 = bf16_hi_val(f0), h1 = bf16_hi_val(f1);
        vh[e]   = bf16_hi_bits(f0); vl[e]   = bf16_hi_bits(f0 - h0);
        vh[4+e] = bf16_hi_bits(f1); vl[4+e] = bf16_hi_bits(f1 - h1);
      }
      *(s16x8*)&Ah[(half*64+r)*32 + sseg*8] = vh;
      *(s16x8*)&Al[(half*64+r)*32 + sseg*8] = vl;
      u32x4 bh = *(const u32x4*)(Bhi + (size_t)(n0 + half*64 + r)*K + kt + sseg*8);
      u32x4 bl = *(const u32x4*)(Blo + (size_t)(n0 + half*64 + r)*K + kt + sseg*8);
      *(u32x4*)&Bh[(half*64+r)*32 + sseg*8] = bh;
      *(u32x4*)&Bl[(half*64+r)*32 + sseg*8] = bl;
    }
    __syncthreads();
    s16x8 afh[4], afl[4], bfh[4], bfl[4];
    int k8 = (lane >> 4) * 8;
    int ra = wm*64 + (lane & 15), rb = wn*64 + (lane & 15);
    #pragma unroll
    for (int mi=0;mi<4;mi++){
      afh[mi] = *(const s16x8*)&Ah[(ra + mi*16)*32 + k8];
      afl[mi] = *(const s16x8*)&Al[(ra + mi*16)*32 + k8];
    }
    #pragma unroll
    for (int ni=0;ni<4;ni++){
      bfh[ni] = *(const s16x8*)&Bh[(rb + ni*16)*32 + k8];
      bfl[ni] = *(const s16x8*)&Bl[(rb + ni*16)*32 + k8];
    }
    #pragma unroll
    for (int mi=0;mi<4;mi++)
      #pragma unroll
      for (int ni=0;ni<4;ni++){
        acc[mi][ni] = __builtin_amdgcn_mfma_f32_16x16x32_bf16(afh[mi], bfh[ni], acc[mi][ni], 0, 0, 0);
        acc[mi][ni] = __builtin_amdgcn_mfma_f32_16x16x32_bf16(afl[mi], bfh[ni], acc[mi][ni], 0, 0, 0);
        acc[mi][ni] = __builtin_amdgcn_mfma_f32_16x16x32_bf16(afh[mi], bfl[ni], acc[mi][ni], 0, 0, 0);
      }
    __syncthreads();
  }
  #pragma unroll
  for (int mi=0;mi<4;mi++)
    #pragma unroll
    for (int ni=0;ni<4;ni++){
      int col  = n0 + wn*64 + ni*16 + (lane & 15);
      int row0 = m0 + wm*64 + mi*16 + (lane >> 4)*4;
      #pragma unroll
      for (int rr=0;rr<4;rr++)
        C[(size_t)(row0+rr)*N + col] = (_Float16)acc[mi][ni][rr];
    }
}

// ---------------------------------------------------------------------------
// LSTM, weights-in-registers: 128 blocks = bq(8) x dir(2) x gate(4) x half(2).
// Block holds its 256-col x 512-k f16 weight slice in VGPRs (32 fragments).
// Per step: register MFMA GEMV -> publish pre-LN f32 half-tile + partial LN
// stats (one LLC round trip) -> read 7 sibling chunks -> replicated LN + cell
// update + c-LN; h stays block-local in LDS as MFMA A-fragments.
// chunk layout (floats): [4b][256cols] + [4b][2 stats]  (stride 1040)
// ---------------------------------------------------------------------------
#define CHUNK 1040

__global__ __launch_bounds__(512, 2) void lstm_fast(
    const _Float16* __restrict__ xp,     // [16384][4096]
    const _Float16* __restrict__ wpk,    // [8 slices][16][32][64][8]
    const float* __restrict__ gg, const float* __restrict__ gb,   // [2][2048]
    const float* __restrict__ cgam, const float* __restrict__ cbet, // [2][512]
    float* __restrict__ out,             // [16384][1024]
    float* __restrict__ tf,              // [16grp][2buf][8chunk][CHUNK]
    unsigned* __restrict__ flags)        // [128*64]
{
  int blk = blockIdx.x;
  int sub = blk & 15;                    // (dir,gate,half) -> XCD spread
  int bq = blk >> 4;
  int dir = sub >> 3, gate = (sub >> 1) & 3, half = sub & 1;
  int tid = threadIdx.x, lane = tid & 63, wv = tid >> 6;
  int b0 = bq * 4;
  int grp = bq*2 + dir;
  int blkbase = (bq << 4) | (dir << 3);
  int own_sub = gate*2 + half;

  __shared__ __align__(16) _Float16 hfrag[16*64*8];   // 16KB A-fragments
  __shared__ float c_s[4][512];                        // 8KB
  __shared__ float red[8][4][2];
  __shared__ float redc[8][4][2];
  __shared__ float sarr[64];
  __shared__ float lnstat[16][2];
  __shared__ float cstat[4][2];

  for (int i = tid; i < 16*64*8; i += 512) hfrag[i] = (_Float16)0.f;
  for (int i = tid; i < 4*512;  i += 512) c_s[i>>9][i&511] = 0.f;
  __syncthreads();

  // ---- load weight slice into registers (once) ----
  const _Float16* wbase = wpk + (size_t)(dir*4 + gate) * (16*32*64*8);
  int c16a = half*16 + wv*2, c16b = c16a + 1;
  f16x8 wA[16], wB[16];
  #pragma unroll
  for (int kt = 0; kt < 16; ++kt){
    wA[kt] = *(const f16x8*)&wbase[(((size_t)kt*32 + c16a)*64 + lane)*8];
    wB[kt] = *(const f16x8*)&wbase[(((size_t)kt*32 + c16b)*64 + lane)*8];
  }

  for (int t = 0; t < 512; ++t){
    int pos = dir ? (511 - t) : t;
    int buf = t & 1;
    // ---- xp loads (independent of h) ----
    float xv0[4], xv1[4];
    if (lane < 16){
      const _Float16* xb = xp + (size_t)(pos*32 + b0)*4096 + dir*2048 + gate*512 + half*256;
      #pragma unroll
      for (int r = 0; r < 4; ++r){
        xv0[r] = (float)xb[(size_t)r*4096 + (wv*2+0)*16 + lane];
        xv1[r] = (float)xb[(size_t)r*4096 + (wv*2+1)*16 + lane];
      }
    }
    // ---- GEMV: pure-register MFMA ----
    f32x4 acc0 = {}, acc1 = {};
    #pragma unroll
    for (int kt = 0; kt < 16; ++kt){
      f16x8 afrag = *(const f16x8*)&hfrag[(kt*64 + lane)*8];
      acc0 = __builtin_amdgcn_mfma_f32_16x16x32_f16(afrag, wA[kt], acc0, 0, 0, 0);
      acc1 = __builtin_amdgcn_mfma_f32_16x16x32_f16(afrag, wB[kt], acc1, 0, 0, 0);
    }
    // ---- pre-LN values + partial stats (lanes 0..15 hold rows b=0..3) ----
    float s[4] = {0,0,0,0}, q[4] = {0,0,0,0};
    if (lane < 16){
      #pragma unroll
      for (int r = 0; r < 4; ++r){
        float v0 = acc0[r] + xv0[r];
        float v1 = acc1[r] + xv1[r];
        acc0[r] = v0; acc1[r] = v1;
        s[r] += v0 + v1; q[r] += v0*v0 + v1*v1;
      }
    }
    #pragma unroll
    for (int o = 1; o < 16; o <<= 1){
      #pragma unroll
      for (int r = 0; r < 4; ++r){ s[r] += __shfl_xor(s[r], o); q[r] += __shfl_xor(q[r], o); }
    }
    if (lane == 0){
      #pragma unroll
      for (int r = 0; r < 4; ++r){ red[wv][r][0] = s[r]; red[wv][r][1] = q[r]; }
    }
    __syncthreads();
    // ---- publish pre-LN half-tile + partial stats ----
    float* chk = tf + ((size_t)(grp*2 + buf)*8 + own_sub)*CHUNK;
    if (lane < 16){
      #pragma unroll
      for (int r = 0; r < 4; ++r){
        agent_store_f(chk + r*256 + (wv*2+0)*16 + lane, acc0[r]);
        agent_store_f(chk + r*256 + (wv*2+1)*16 + lane, acc1[r]);
      }
    }
    if (tid < 8){
      int b = tid >> 1, wh = tid & 1;
      float S = 0.f;
      #pragma unroll
      for (int w = 0; w < 8; ++w) S += red[w][b][wh];
      agent_store_f(chk + 1024 + b*2 + wh, S);
    }
    asm volatile("s_waitcnt vmcnt(0)" ::: "memory");
    __syncthreads();
    if (tid == 0)
      __hip_atomic_store(&flags[blk*64], (unsigned)(t+1), __ATOMIC_RELAXED, __HIP_MEMORY_SCOPE_AGENT);
    // ---- wait for 7 siblings ----
    if (tid < 7){
      int idx = tid < own_sub ? tid : tid + 1;
      int sblk = blkbase + idx;
      while (__hip_atomic_load(&flags[sblk*64], __ATOMIC_RELAXED, __HIP_MEMORY_SCOPE_AGENT)
             < (unsigned)(t+1))
        __builtin_amdgcn_s_sleep(1);
    }
    __syncthreads();
    // ---- gather stats (2 halves per gate) ----
    const float* gbase = tf + ((size_t)(grp*2 + buf)*8)*CHUNK;
    if (tid < 64){
      int g = tid >> 4, b = (tid >> 2) & 3, hf2 = (tid >> 1) & 1, wh = tid & 1;
      sarr[tid] = agent_load_f(gbase + (size_t)(g*2 + hf2)*CHUNK + 1024 + b*2 + wh);
    }
    __syncthreads();
    if (tid < 16){
      int g = tid >> 2, b = tid & 3;
      float S = sarr[g*16 + b*4 + 0] + sarr[g*16 + b*4 + 2];
      float Q = sarr[g*16 + b*4 + 1] + sarr[g*16 + b*4 + 3];
      float mean = S*(1.0f/512.0f);
      float var  = Q*(1.0f/512.0f) - mean*mean;
      lnstat[tid][0] = mean; lnstat[tid][1] = rsqrtf(var + LN_EPS);
    }
    __syncthreads();
    // ---- read pre-LN tiles, LN, cell update (replicated) ----
    {
      int hf = tid >> 8, c = tid & 255;
      const float* cb0p = gbase + (size_t)(0*2 + hf)*CHUNK + c;
      const float* cb1p = gbase + (size_t)(1*2 + hf)*CHUNK + c;
      const float* cb2p = gbase + (size_t)(2*2 + hf)*CHUNK + c;
      const float* cb3p = gbase + (size_t)(3*2 + hf)*CHUNK + c;
      float p0[4], p1[4], p2[4], p3[4];
      #pragma unroll
      for (int b = 0; b < 4; ++b){
        p0[b] = agent_load_f(cb0p + b*256);
        p1[b] = agent_load_f(cb1p + b*256);
        p2[b] = agent_load_f(cb2p + b*256);
        p3[b] = agent_load_f(cb3p + b*256);
      }
      int j = tid;
      float g0s = gg[dir*2048 + 0*512 + j], g0b = gb[dir*2048 + 0*512 + j];
      float g1s = gg[dir*2048 + 1*512 + j], g1b = gb[dir*2048 + 1*512 + j];
      float g2s = gg[dir*2048 + 2*512 + j], g2b = gb[dir*2048 + 2*512 + j];
      float g3s = gg[dir*2048 + 3*512 + j], g3b = gb[dir*2048 + 3*512 + j];
      float cs[4], cq[4], ov[4];
      #pragma unroll
      for (int b = 0; b < 4; ++b){
        float pi = (p0[b] - lnstat[0*4+b][0])*lnstat[0*4+b][1]*g0s + g0b;
        float pf = (p1[b] - lnstat[1*4+b][0])*lnstat[1*4+b][1]*g1s + g1b;
        float pv = (p2[b] - lnstat[2*4+b][0])*lnstat[2*4+b][1]*g2s + g2b;
        ov[b]    = (p3[b] - lnstat[3*4+b][0])*lnstat[3*4+b][1]*g3s + g3b;
        float cn = sigmoidf_(pf)*c_s[b][j] + sigmoidf_(pi)*tanhf(pv);
        c_s[b][j] = cn;
        cs[b] = cn; cq[b] = cn*cn;
      }
      #pragma unroll
      for (int o = 1; o < 64; o <<= 1){
        #pragma unroll
        for (int b = 0; b < 4; ++b){ cs[b] += __shfl_xor(cs[b], o); cq[b] += __shfl_xor(cq[b], o); }
      }
      if (lane == 0){
        #pragma unroll
        for (int b = 0; b < 4; ++b){ redc[wv][b][0] = cs[b]; redc[wv][b][1] = cq[b]; }
      }
      __syncthreads();
      if (tid < 4){
        float S = 0.f, Q = 0.f;
        #pragma unroll
        for (int w = 0; w < 8; ++w){ S += redc[w][tid][0]; Q += redc[w][tid][1]; }
        float mean = S*(1.0f/512.0f);
        float var  = Q*(1.0f/512.0f) - mean*mean;
        cstat[tid][0] = mean; cstat[tid][1] = rsqrtf(var + LN_EPS);
      }
      __syncthreads();
      float cgv = cgam[dir*512 + j], cbv = cbet[dir*512 + j];
      #pragma unroll
      for (int b = 0; b < 4; ++b){
        float cl = (c_s[b][j] - cstat[b][0])*cstat[b][1]*cgv + cbv;
        float hv = sigmoidf_(ov[b]) * tanhf(cl);
        hfrag[(((j >> 5)*64) + ((j & 31) >> 3)*16 + b)*8 + (j & 7)] = (_Float16)hv;
        if (own_sub == 0)
          out[(size_t)(pos*32 + b0 + b)*1024 + dir*512 + j] = hv;
      }
    }
    __syncthreads();
  }
}

// ---------------------------------------------------------------------------
__global__ void k_bn2_stats(const float* __restrict__ h1, float* __restrict__ stats){
  int tid = threadIdx.x;
  int c4 = tid*4;
  float s[4]={0,0,0,0}, q[4]={0,0,0,0};
  int rbase = blockIdx.x*64;
  for (int i=0;i<64;i++){
    f32x4 v = *(const f32x4*)(h1 + (size_t)(rbase+i)*1024 + c4);
    #pragma unroll
    for (int e=0;e<4;e++){ s[e]+=v[e]; q[e]+=v[e]*v[e]; }
  }
  #pragma unroll
  for (int e=0;e<4;e++){
    atomicAdd(&stats[c4+e], s[e]);
    atomicAdd(&stats[1024+c4+e], q[e]);
  }
}

__global__ void k_bn2_fin(const float* __restrict__ stats, const float* __restrict__ gamma,
                          const float* __restrict__ beta, float* __restrict__ ss){
  int c = blockIdx.x*256 + threadIdx.x;
  if (c < 1024){
    float N = 16384.0f;
    float mean = stats[c]/N;
    float var  = stats[1024+c]/N - mean*mean;
    float scale = gamma[c] * rsqrtf(var + LN_EPS);
    ss[c] = scale;
    ss[1024+c] = beta[c] - mean*scale;
  }
}

__global__ void k_att1(const float* __restrict__ h1, const float* __restrict__ ss,
                       const float* __restrict__ wom, const float* __restrict__ bom,
                       const float* __restrict__ uom, float* __restrict__ vu){
  __shared__ float tmp[4][64];
  int tid = threadIdx.x, wave = tid >> 6, ln = tid & 63;
  int part = ln/20, a = ln - part*20;
  bool active = (part < 3);
  for (int rr = 0; rr < 4; ++rr){
    int row = blockIdx.x*16 + wave*4 + rr;
    float acc = 0.0f;
    if (active){
      int n0 = part*342, n1 = (part==2) ? 1024 : (n0+342);
      for (int n = n0; n < n1; ++n){
        float hv = h1[(size_t)row*1024 + n]*ss[n] + ss[1024+n];
        acc += hv * wom[n*20 + a];
      }
    }
    tmp[wave][ln] = acc;
    __syncthreads();
    float pv = 0.0f;
    if (ln < 20){
      float v = tanhf(tmp[wave][ln] + tmp[wave][ln+20] + tmp[wave][ln+40] + bom[ln]);
      pv = v*uom[ln];
    }
    #pragma unroll
    for (int o=1;o<32;o<<=1) pv += __shfl_xor(pv, o);
    if (ln == 0) vu[row] = pv;
    __syncthreads();
  }
}

__global__ void k_att3(const float* __restrict__ h1, const float* __restrict__ ss,
                       const float* __restrict__ vu, float* __restrict__ out){
  __shared__ float al[512];
  __shared__ float red[4];
  int tid = threadIdx.x;
  int b = blockIdx.x >> 3, ch = blockIdx.x & 7;
  for (int t = tid; t < 512; t += 128) al[t] = vu[t*32 + b];
  __syncthreads();
  float m = -1e30f;
  for (int t = tid; t < 512; t += 128) m = fmaxf(m, al[t]);
  #pragma unroll
  for (int o=1;o<64;o<<=1) m = fmaxf(m, __shfl_xor(m,o));
  if ((tid & 63) == 0) red[tid>>6] = m;
  __syncthreads();
  m = fmaxf(red[0], red[1]);
  float s = 0.0f;
  for (int t = tid; t < 512; t += 128){ float e = expf(al[t]-m); al[t] = e; s += e; }
  #pragma unroll
  for (int o=1;o<64;o<<=1) s += __shfl_xor(s,o);
  if ((tid & 63) == 0) red[2 + (tid>>6)] = s;
  __syncthreads();
  float inv = 1.0f / (red[2] + red[3]);
  int n = ch*128 + tid;
  float acc = 0.0f;
  #pragma unroll 4
  for (int t = 0; t < 512; ++t) acc += al[t]*h1[(size_t)(t*32+b)*1024 + n];
  out[b*1024 + n] = acc*inv*ss[n] + ss[1024+n];
}

// ---------------------------------------------------------------------------
extern "C" void kernel_launch(void* const* d_in, const int* in_sizes, int n_in,
                              void* d_out, int out_size, void* d_ws, size_t ws_size,
                              hipStream_t stream){
  const float* x    = (const float*)d_in[0];
  const float* bn1g = (const float*)d_in[1];
  const float* bn1b = (const float*)d_in[2];
  const float* bn2g = (const float*)d_in[3];
  const float* bn2b = (const float*)d_in[4];
  const float* wih0 = (const float*)d_in[5];
  const float* whh0 = (const float*)d_in[6];
  const float* gg0  = (const float*)d_in[7];
  const float* gb0  = (const float*)d_in[8];
  const float* cg0  = (const float*)d_in[9];
  const float* cb0  = (const float*)d_in[10];
  const float* wih1 = (const float*)d_in[11];
  const float* whh1 = (const float*)d_in[12];
  const float* gg1  = (const float*)d_in[13];
  const float* gb1  = (const float*)d_in[14];
  const float* cg1  = (const float*)d_in[15];
  const float* cb1  = (const float*)d_in[16];
  const float* wom  = (const float*)d_in[17];
  const float* bom  = (const float*)d_in[18];
  const float* uom  = (const float*)d_in[19];
  float* out = (float*)d_out;

  char* w = (char*)d_ws;
  size_t off = 0;
  auto take = [&](size_t bytes)->void*{
    void* p = w + off;
    off += (bytes + 255) & ~(size_t)255;
    return p;
  };
  _Float16* xp = (_Float16*)take(16384ull*4096*2);      // 128 MB
  float* hA = (float*)take(16384ull*1024*4);            // 64 MB
  __hip_bfloat16* w0hi = (__hip_bfloat16*)take(4096ull*128*2);
  __hip_bfloat16* w0lo = (__hip_bfloat16*)take(4096ull*128*2);
  __hip_bfloat16* w1hi = (__hip_bfloat16*)take(4096ull*1024*2);
  __hip_bfloat16* w1lo = (__hip_bfloat16*)take(4096ull*1024*2);
  _Float16* wpk0 = (_Float16*)take(2ull*2048*512*2);    // 4 MB
  _Float16* wpk1 = (_Float16*)take(2ull*2048*512*2);    // 4 MB
  float* tilesf = (float*)take(16ull*2*8*CHUNK*4);      // ~1.06 MB
  unsigned* flags = (unsigned*)take(128ull*64*4);       // 32 KB
  float* stats1 = (float*)take(256*4);
  float* ss1    = (float*)take(256*4);
  float* stats2 = (float*)take(2048*4);
  float* ss2    = (float*)take(2048*4);
  float* vu     = (float*)take(16384ull*4);
  (void)ws_size; (void)in_sizes; (void)n_in; (void)out_size;

  hipMemsetAsync(stats1, 0, 256*4, stream);
  hipMemsetAsync(stats2, 0, 2048*4, stream);

  k_bn1_stats<<<256,256,0,stream>>>(x, stats1);
  k_bn1_fin<<<1,128,0,stream>>>(stats1, bn1g, bn1b, ss1);
  k_cvt_split<<<256,256,0,stream>>>(wih0, w0hi, w0lo, 4096*128);
  k_cvt_split<<<2048,256,0,stream>>>(wih1, w1hi, w1lo, 4096*1024);
  k_pack_whh<<<8192,256,0,stream>>>(whh0, wpk0);
  k_pack_whh<<<8192,256,0,stream>>>(whh1, wpk1);

  // GEMM0: xp = bn1(x) @ w_ih0^T
  gemm_split<<<dim3(32,128),256,0,stream>>>(x, w0hi, w0lo, xp, 16384, 4096, 128, 1, ss1);

  // ---- layer 0 ----
  hipMemsetAsync(flags, 0, 128*64*4, stream);
  lstm_fast<<<128,512,0,stream>>>(xp, wpk0, gg0, gb0, cg0, cb0, hA, tilesf, flags);

  // GEMM1: xp = h0 @ w_ih1^T
  gemm_split<<<dim3(32,128),256,0,stream>>>(hA, w1hi, w1lo, xp, 16384, 4096, 1024, 0, nullptr);

  // ---- layer 1 ----
  hipMemsetAsync(flags, 0, 128*64*4, stream);
  lstm_fast<<<128,512,0,stream>>>(xp, wpk1, gg1, gb1, cg1, cb1, hA, tilesf, flags);

  k_bn2_stats<<<256,256,0,stream>>>(hA, stats2);
  k_bn2_fin<<<4,256,0,stream>>>(stats2, bn2g, bn2b, ss2);
  k_att1<<<1024,256,0,stream>>>(hA, ss2, wom, bom, uom, vu);
  k_att3<<<256,128,0,stream>>>(hA, ss2, vu, out);
}

// Round 8
// 7611.397 us; speedup vs baseline: 10.7478x; 1.1229x over previous
//
#include <hip/hip_runtime.h>
#include <hip/hip_bf16.h>

#define LN_EPS 1e-5f

typedef __attribute__((ext_vector_type(4))) float    f32x4;
typedef __attribute__((ext_vector_type(8))) short    s16x8;
typedef __attribute__((ext_vector_type(8))) _Float16 f16x8;
typedef __attribute__((ext_vector_type(4))) unsigned u32x4;

__device__ __forceinline__ float sigmoidf_(float x){ return 1.0f/(1.0f+expf(-x)); }

// fast transcendentals (v_exp based); abs err ~1e-6, fine vs 9.8e-3 budget
__device__ __forceinline__ float fsig(float x){
  return 1.0f/(1.0f + __expf(-x));
}
__device__ __forceinline__ float ftanh(float x){
  float xx = fminf(fmaxf(x, -15.f), 15.f);
  float e = __expf(2.f*xx);
  return (e - 1.f)/(e + 1.f);
}

__device__ __forceinline__ short bf16_hi_bits(float f){
  __hip_bfloat16 h = __float2bfloat16(f);
  return *reinterpret_cast<short*>(&h);
}
__device__ __forceinline__ float bf16_hi_val(float f){
  return __bfloat162float(__float2bfloat16(f));
}

__device__ __forceinline__ float agent_load_f(const float* p){
  return __hip_atomic_load((float*)p, __ATOMIC_RELAXED, __HIP_MEMORY_SCOPE_AGENT);
}
__device__ __forceinline__ void agent_store_f(float* p, float v){
  __hip_atomic_store(p, v, __ATOMIC_RELAXED, __HIP_MEMORY_SCOPE_AGENT);
}

// ---------------------------------------------------------------------------
// bn1
// ---------------------------------------------------------------------------
__global__ void k_bn1_stats(const float* __restrict__ x, float* __restrict__ stats){
  int tid = threadIdx.x;
  int cg = tid >> 3, ro = tid & 7;
  int c4 = cg * 4;
  float s[4] = {0,0,0,0}, q[4] = {0,0,0,0};
  int rbase = blockIdx.x * 64;
  for (int i = 0; i < 8; ++i){
    int row = rbase + i*8 + ro;
    f32x4 v = *(const f32x4*)(x + (size_t)row*128 + c4);
    #pragma unroll
    for (int e=0;e<4;e++){ s[e]+=v[e]; q[e]+=v[e]*v[e]; }
  }
  #pragma unroll
  for (int o=1;o<8;o<<=1){
    #pragma unroll
    for (int e=0;e<4;e++){ s[e]+=__shfl_xor(s[e],o); q[e]+=__shfl_xor(q[e],o); }
  }
  if (ro==0){
    #pragma unroll
    for (int e=0;e<4;e++){
      atomicAdd(&stats[c4+e], s[e]);
      atomicAdd(&stats[128+c4+e], q[e]);
    }
  }
}

__global__ void k_bn1_fin(const float* __restrict__ stats, const float* __restrict__ gamma,
                          const float* __restrict__ beta, float* __restrict__ ss){
  int c = threadIdx.x;
  if (c < 128){
    float N = 16384.0f;
    float mean = stats[c]/N;
    float var  = stats[128+c]/N - mean*mean;
    float scale = gamma[c] * rsqrtf(var + LN_EPS);
    ss[c] = scale;
    ss[128+c] = beta[c] - mean*scale;
  }
}

// split f32 -> (hi, lo) bf16 pair
__global__ void k_cvt_split(const float* __restrict__ s, __hip_bfloat16* __restrict__ hi,
                            __hip_bfloat16* __restrict__ lo, int n){
  for (int i = blockIdx.x*blockDim.x + threadIdx.x; i < n; i += gridDim.x*blockDim.x){
    float v = s[i];
    __hip_bfloat16 h = __float2bfloat16(v);
    hi[i] = h;
    lo[i] = __float2bfloat16(v - __bfloat162float(h));
  }
}

// pack whh [2][2048][512] f32 -> fragment-linear f16
// wpk[(dir*4+gate)][kt=16][c16=32][lane=64][8]
__global__ void k_pack_whh(const float* __restrict__ whh, _Float16* __restrict__ wpk){
  size_t i = (size_t)blockIdx.x*256 + threadIdx.x;     // over 2*2048*512
  int k = (int)(i & 511);
  size_t ci = i >> 9;
  int col = (int)(ci & 2047);
  int dirr = (int)(ci >> 11);
  int gate = col >> 9, cig = col & 511, c16 = cig >> 4, lc = cig & 15;
  int kt = k >> 5, ksub = k & 31, hi = ksub >> 3, j = ksub & 7;
  size_t dst = ((((size_t)(dirr*4+gate)*16 + kt)*32 + c16)*64 + (hi*16+lc))*8 + j;
  wpk[dst] = (_Float16)whh[i];
}

// ---------------------------------------------------------------------------
// Split-bf16 fp32-accurate GEMM: C[M][N] = A[M][K] * B[N][K]^T, C fp16.
// ---------------------------------------------------------------------------
__global__ __launch_bounds__(256) void gemm_split(const float* __restrict__ A,
                                                  const __hip_bfloat16* __restrict__ Bhi,
                                                  const __hip_bfloat16* __restrict__ Blo,
                                                  _Float16* __restrict__ C,
                                                  int M, int N, int K,
                                                  int a_mode, const float* __restrict__ ss){
  __shared__ __align__(16) __hip_bfloat16 Ah[128*32];
  __shared__ __align__(16) __hip_bfloat16 Al[128*32];
  __shared__ __align__(16) __hip_bfloat16 Bh[128*32];
  __shared__ __align__(16) __hip_bfloat16 Bl[128*32];
  int n0 = blockIdx.x * 128, m0 = blockIdx.y * 128;
  int tid = threadIdx.x, lane = tid & 63, wave = tid >> 6;
  int wm = wave >> 1, wn = wave & 1;
  f32x4 acc[4][4] = {};
  int r = tid >> 2, sseg = tid & 3;
  for (int kt = 0; kt < K; kt += 32){
    #pragma unroll
    for (int half = 0; half < 2; ++half){
      int m = m0 + half*64 + r;
      const float* src;
      if (a_mode){
        int t = m >> 5, b = m & 31;
        src = A + ((size_t)(b*512 + t))*128 + kt + sseg*8;
      } else {
        src = A + (size_t)m*K + kt + sseg*8;
      }
      f32x4 v0 = *(const f32x4*)src;
      f32x4 v1 = *(const f32x4*)(src + 4);
      s16x8 vh, vl;
      #pragma unroll
      for (int e=0;e<4;e++){
        float f0 = v0[e], f1 = v1[e];
        if (a_mode){
          int k = kt + sseg*8;
          f0 = f0*ss[k+e]   + ss[128+k+e];
          f1 = f1*ss[k+4+e] + ss[128+k+4+e];
        }
        float h0 = bf16_hi_val(f0), h1 = bf16_hi_val(f1);
        vh[e]   = bf16_hi_bits(f0); vl[e]   = bf16_hi_bits(f0 - h0);
        vh[4+e] = bf16_hi_bits(f1); vl[4+e] = bf16_hi_bits(f1 - h1);
      }
      *(s16x8*)&Ah[(half*64+r)*32 + sseg*8] = vh;
      *(s16x8*)&Al[(half*64+r)*32 + sseg*8] = vl;
      u32x4 bh = *(const u32x4*)(Bhi + (size_t)(n0 + half*64 + r)*K + kt + sseg*8);
      u32x4 bl = *(const u32x4*)(Blo + (size_t)(n0 + half*64 + r)*K + kt + sseg*8);
      *(u32x4*)&Bh[(half*64+r)*32 + sseg*8] = bh;
      *(u32x4*)&Bl[(half*64+r)*32 + sseg*8] = bl;
    }
    __syncthreads();
    s16x8 afh[4], afl[4], bfh[4], bfl[4];
    int k8 = (lane >> 4) * 8;
    int ra = wm*64 + (lane & 15), rb = wn*64 + (lane & 15);
    #pragma unroll
    for (int mi=0;mi<4;mi++){
      afh[mi] = *(const s16x8*)&Ah[(ra + mi*16)*32 + k8];
      afl[mi] = *(const s16x8*)&Al[(ra + mi*16)*32 + k8];
    }
    #pragma unroll
    for (int ni=0;ni<4;ni++){
      bfh[ni] = *(const s16x8*)&Bh[(rb + ni*16)*32 + k8];
      bfl[ni] = *(const s16x8*)&Bl[(rb + ni*16)*32 + k8];
    }
    #pragma unroll
    for (int mi=0;mi<4;mi++)
      #pragma unroll
      for (int ni=0;ni<4;ni++){
        acc[mi][ni] = __builtin_amdgcn_mfma_f32_16x16x32_bf16(afh[mi], bfh[ni], acc[mi][ni], 0, 0, 0);
        acc[mi][ni] = __builtin_amdgcn_mfma_f32_16x16x32_bf16(afl[mi], bfh[ni], acc[mi][ni], 0, 0, 0);
        acc[mi][ni] = __builtin_amdgcn_mfma_f32_16x16x32_bf16(afh[mi], bfl[ni], acc[mi][ni], 0, 0, 0);
      }
    __syncthreads();
  }
  #pragma unroll
  for (int mi=0;mi<4;mi++)
    #pragma unroll
    for (int ni=0;ni<4;ni++){
      int col  = n0 + wn*64 + ni*16 + (lane & 15);
      int row0 = m0 + wm*64 + mi*16 + (lane >> 4)*4;
      #pragma unroll
      for (int rr=0;rr<4;rr++)
        C[(size_t)(row0+rr)*N + col] = (_Float16)acc[mi][ni][rr];
    }
}

// ---------------------------------------------------------------------------
// LSTM, weights-in-registers (forced): 128 blocks = bq(8)x dir(2)x gate(4)x half(2).
// asm memory clobber after the weight load pins the 32 f16x8 fragments in VGPRs
// (blocks compiler rematerialization that R7's counters exposed: VGPR=112 < 128).
// Per step: register MFMA GEMV -> publish pre-LN f32 half-tile (early) + stats
// -> flag -> poll -> merged sc1 reads (tiles + stats in one round trip) ->
// replicated LN + cell update (fast sigmoid/tanh) -> h to LDS A-fragments.
// chunk layout (floats): [4b][256cols] + [4b][2 stats]  (stride 1040)
// ---------------------------------------------------------------------------
#define CHUNK 1040

__global__ __launch_bounds__(512, 2) void lstm_fast(
    const _Float16* __restrict__ xp,     // [16384][4096]
    const _Float16* __restrict__ wpk,    // [8 slices][16][32][64][8]
    const float* __restrict__ gg, const float* __restrict__ gb,   // [2][2048]
    const float* __restrict__ cgam, const float* __restrict__ cbet, // [2][512]
    float* __restrict__ out,             // [16384][1024]
    float* __restrict__ tf,              // [16grp][2buf][8chunk][CHUNK]
    unsigned* __restrict__ flags)        // [128*64]
{
  int blk = blockIdx.x;
  int sub = blk & 15;                    // (dir,gate,half) -> XCD spread
  int bq = blk >> 4;
  int dir = sub >> 3, gate = (sub >> 1) & 3, half = sub & 1;
  int tid = threadIdx.x, lane = tid & 63, wv = tid >> 6;
  int b0 = bq * 4;
  int grp = bq*2 + dir;
  int blkbase = (bq << 4) | (dir << 3);
  int own_sub = gate*2 + half;

  __shared__ __align__(16) _Float16 hfrag[16*64*8];   // 16KB A-fragments
  __shared__ float c_s[4][512];                        // 8KB
  __shared__ float red[8][4][2];
  __shared__ float redc[8][4][2];
  __shared__ float sarr[64];
  __shared__ float lnstat[16][2];
  __shared__ float cstat[4][2];

  for (int i = tid; i < 16*64*8; i += 512) hfrag[i] = (_Float16)0.f;
  for (int i = tid; i < 4*512;  i += 512) c_s[i>>9][i&511] = 0.f;
  __syncthreads();

  // ---- hoist loop-invariant LN/cell params (pinned by the clobber below) ----
  int j = tid;
  float g0s = gg[dir*2048 + j],        g0b = gb[dir*2048 + j];
  float g1s = gg[dir*2048 + 512 + j],  g1b = gb[dir*2048 + 512 + j];
  float g2s = gg[dir*2048 + 1024 + j], g2b = gb[dir*2048 + 1024 + j];
  float g3s = gg[dir*2048 + 1536 + j], g3b = gb[dir*2048 + 1536 + j];
  float cgv = cgam[dir*512 + j],       cbv = cbet[dir*512 + j];

  // ---- load weight slice into registers (once, FORCED resident) ----
  const _Float16* wbase = wpk + (size_t)(dir*4 + gate) * (16*32*64*8);
  int c16a = half*16 + wv*2, c16b = c16a + 1;
  f16x8 wA[16], wB[16];
  #pragma unroll
  for (int kt = 0; kt < 16; ++kt){
    wA[kt] = *(const f16x8*)&wbase[(((size_t)kt*32 + c16a)*64 + lane)*8];
    wB[kt] = *(const f16x8*)&wbase[(((size_t)kt*32 + c16b)*64 + lane)*8];
  }
  // memory clobber: compiler may no longer re-derive wA/wB (or the hoisted
  // params) from memory -> they must stay in VGPRs for the whole loop.
  asm volatile("" ::: "memory");

  for (int t = 0; t < 512; ++t){
    int pos = dir ? (511 - t) : t;
    int buf = t & 1;
    // ---- xp loads (independent of h) ----
    float xv0[4], xv1[4];
    if (lane < 16){
      const _Float16* xb = xp + (size_t)(pos*32 + b0)*4096 + dir*2048 + gate*512 + half*256;
      #pragma unroll
      for (int r = 0; r < 4; ++r){
        xv0[r] = (float)xb[(size_t)r*4096 + (wv*2+0)*16 + lane];
        xv1[r] = (float)xb[(size_t)r*4096 + (wv*2+1)*16 + lane];
      }
    }
    // ---- GEMV: pure-register MFMA ----
    f32x4 acc0 = {}, acc1 = {};
    #pragma unroll
    for (int kt = 0; kt < 16; ++kt){
      f16x8 afrag = *(const f16x8*)&hfrag[(kt*64 + lane)*8];
      acc0 = __builtin_amdgcn_mfma_f32_16x16x32_f16(afrag, wA[kt], acc0, 0, 0, 0);
      acc1 = __builtin_amdgcn_mfma_f32_16x16x32_f16(afrag, wB[kt], acc1, 0, 0, 0);
    }
    // ---- pre-LN values + partial stats (lanes 0..15 hold rows b=0..3) ----
    float s[4] = {0,0,0,0}, q[4] = {0,0,0,0};
    if (lane < 16){
      #pragma unroll
      for (int r = 0; r < 4; ++r){
        float v0 = acc0[r] + xv0[r];
        float v1 = acc1[r] + xv1[r];
        acc0[r] = v0; acc1[r] = v1;
        s[r] += v0 + v1; q[r] += v0*v0 + v1*v1;
      }
    }
    #pragma unroll
    for (int o = 1; o < 16; o <<= 1){
      #pragma unroll
      for (int r = 0; r < 4; ++r){ s[r] += __shfl_xor(s[r], o); q[r] += __shfl_xor(q[r], o); }
    }
    if (lane == 0){
      #pragma unroll
      for (int r = 0; r < 4; ++r){ red[wv][r][0] = s[r]; red[wv][r][1] = q[r]; }
    }
    // ---- publish pre-LN half-tile EARLY (overlaps with red[] sync) ----
    float* chk = tf + ((size_t)(grp*2 + buf)*8 + own_sub)*CHUNK;
    if (lane < 16){
      #pragma unroll
      for (int r = 0; r < 4; ++r){
        agent_store_f(chk + r*256 + (wv*2+0)*16 + lane, acc0[r]);
        agent_store_f(chk + r*256 + (wv*2+1)*16 + lane, acc1[r]);
      }
    }
    __syncthreads();                 // red[] ready
    if (tid < 8){
      int b = tid >> 1, wh = tid & 1;
      float S = 0.f;
      #pragma unroll
      for (int w = 0; w < 8; ++w) S += red[w][b][wh];
      agent_store_f(chk + 1024 + b*2 + wh, S);
    }
    asm volatile("s_waitcnt vmcnt(0)" ::: "memory");
    __syncthreads();                 // all waves drained
    if (tid == 0)
      __hip_atomic_store(&flags[blk*64], (unsigned)(t+1), __ATOMIC_RELAXED, __HIP_MEMORY_SCOPE_AGENT);
    // ---- wait for 7 siblings ----
    if (tid < 7){
      int idx = tid < own_sub ? tid : tid + 1;
      int sblk = blkbase + idx;
      while (__hip_atomic_load(&flags[sblk*64], __ATOMIC_RELAXED, __HIP_MEMORY_SCOPE_AGENT)
             < (unsigned)(t+1))
        __builtin_amdgcn_s_sleep(1);
    }
    __syncthreads();
    // ---- merged reads: tiles into regs + stats into LDS, one round trip ----
    const float* gbase = tf + ((size_t)(grp*2 + buf)*8)*CHUNK;
    int hf = tid >> 8, c = tid & 255;
    const float* q0p = gbase + (size_t)(0*2 + hf)*CHUNK + c;
    const float* q1p = gbase + (size_t)(1*2 + hf)*CHUNK + c;
    const float* q2p = gbase + (size_t)(2*2 + hf)*CHUNK + c;
    const float* q3p = gbase + (size_t)(3*2 + hf)*CHUNK + c;
    float p0[4], p1[4], p2[4], p3[4];
    #pragma unroll
    for (int b = 0; b < 4; ++b){
      p0[b] = agent_load_f(q0p + b*256);
      p1[b] = agent_load_f(q1p + b*256);
      p2[b] = agent_load_f(q2p + b*256);
      p3[b] = agent_load_f(q3p + b*256);
    }
    if (tid < 64){
      int g2_ = tid >> 4, b_ = (tid >> 2) & 3, hf2 = (tid >> 1) & 1, wh = tid & 1;
      sarr[tid] = agent_load_f(gbase + (size_t)(g2_*2 + hf2)*CHUNK + 1024 + b_*2 + wh);
    }
    __syncthreads();                 // sarr ready (tile regs ride along)
    if (tid < 16){
      int g2_ = tid >> 2, b_ = tid & 3;
      float S = sarr[g2_*16 + b_*4 + 0] + sarr[g2_*16 + b_*4 + 2];
      float Q = sarr[g2_*16 + b_*4 + 1] + sarr[g2_*16 + b_*4 + 3];
      float mean = S*(1.0f/512.0f);
      float var  = Q*(1.0f/512.0f) - mean*mean;
      lnstat[tid][0] = mean; lnstat[tid][1] = rsqrtf(var + LN_EPS);
    }
    __syncthreads();
    // ---- LN + cell update (replicated), fast transcendentals ----
    float cs[4], cq[4], ov[4];
    #pragma unroll
    for (int b = 0; b < 4; ++b){
      float pi = (p0[b] - lnstat[0*4+b][0])*lnstat[0*4+b][1]*g0s + g0b;
      float pf = (p1[b] - lnstat[1*4+b][0])*lnstat[1*4+b][1]*g1s + g1b;
      float pv = (p2[b] - lnstat[2*4+b][0])*lnstat[2*4+b][1]*g2s + g2b;
      ov[b]    = (p3[b] - lnstat[3*4+b][0])*lnstat[3*4+b][1]*g3s + g3b;
      float cn = fsig(pf)*c_s[b][j] + fsig(pi)*ftanh(pv);
      c_s[b][j] = cn;
      cs[b] = cn; cq[b] = cn*cn;
    }
    #pragma unroll
    for (int o = 1; o < 64; o <<= 1){
      #pragma unroll
      for (int b = 0; b < 4; ++b){ cs[b] += __shfl_xor(cs[b], o); cq[b] += __shfl_xor(cq[b], o); }
    }
    if (lane == 0){
      #pragma unroll
      for (int b = 0; b < 4; ++b){ redc[wv][b][0] = cs[b]; redc[wv][b][1] = cq[b]; }
    }
    __syncthreads();
    if (tid < 4){
      float S = 0.f, Q = 0.f;
      #pragma unroll
      for (int w = 0; w < 8; ++w){ S += redc[w][tid][0]; Q += redc[w][tid][1]; }
      float mean = S*(1.0f/512.0f);
      float var  = Q*(1.0f/512.0f) - mean*mean;
      cstat[tid][0] = mean; cstat[tid][1] = rsqrtf(var + LN_EPS);
    }
    __syncthreads();
    #pragma unroll
    for (int b = 0; b < 4; ++b){
      float cl = (c_s[b][j] - cstat[b][0])*cstat[b][1]*cgv + cbv;
      float hv = fsig(ov[b]) * ftanh(cl);
      hfrag[(((j >> 5)*64) + ((j & 31) >> 3)*16 + b)*8 + (j & 7)] = (_Float16)hv;
      if (own_sub == 0)
        out[(size_t)(pos*32 + b0 + b)*1024 + dir*512 + j] = hv;
    }
    __syncthreads();
  }
}

// ---------------------------------------------------------------------------
__global__ void k_bn2_stats(const float* __restrict__ h1, float* __restrict__ stats){
  int tid = threadIdx.x;
  int c4 = tid*4;
  float s[4]={0,0,0,0}, q[4]={0,0,0,0};
  int rbase = blockIdx.x*64;
  for (int i=0;i<64;i++){
    f32x4 v = *(const f32x4*)(h1 + (size_t)(rbase+i)*1024 + c4);
    #pragma unroll
    for (int e=0;e<4;e++){ s[e]+=v[e]; q[e]+=v[e]*v[e]; }
  }
  #pragma unroll
  for (int e=0;e<4;e++){
    atomicAdd(&stats[c4+e], s[e]);
    atomicAdd(&stats[1024+c4+e], q[e]);
  }
}

__global__ void k_bn2_fin(const float* __restrict__ stats, const float* __restrict__ gamma,
                          const float* __restrict__ beta, float* __restrict__ ss){
  int c = blockIdx.x*256 + threadIdx.x;
  if (c < 1024){
    float N = 16384.0f;
    float mean = stats[c]/N;
    float var  = stats[1024+c]/N - mean*mean;
    float scale = gamma[c] * rsqrtf(var + LN_EPS);
    ss[c] = scale;
    ss[1024+c] = beta[c] - mean*scale;
  }
}

__global__ void k_att1(const float* __restrict__ h1, const float* __restrict__ ss,
                       const float* __restrict__ wom, const float* __restrict__ bom,
                       const float* __restrict__ uom, float* __restrict__ vu){
  __shared__ float tmp[4][64];
  int tid = threadIdx.x, wave = tid >> 6, ln = tid & 63;
  int part = ln/20, a = ln - part*20;
  bool active = (part < 3);
  for (int rr = 0; rr < 4; ++rr){
    int row = blockIdx.x*16 + wave*4 + rr;
    float acc = 0.0f;
    if (active){
      int n0 = part*342, n1 = (part==2) ? 1024 : (n0+342);
      for (int n = n0; n < n1; ++n){
        float hv = h1[(size_t)row*1024 + n]*ss[n] + ss[1024+n];
        acc += hv * wom[n*20 + a];
      }
    }
    tmp[wave][ln] = acc;
    __syncthreads();
    float pv = 0.0f;
    if (ln < 20){
      float v = tanhf(tmp[wave][ln] + tmp[wave][ln+20] + tmp[wave][ln+40] + bom[ln]);
      pv = v*uom[ln];
    }
    #pragma unroll
    for (int o=1;o<32;o<<=1) pv += __shfl_xor(pv, o);
    if (ln == 0) vu[row] = pv;
    __syncthreads();
  }
}

__global__ void k_att3(const float* __restrict__ h1, const float* __restrict__ ss,
                       const float* __restrict__ vu, float* __restrict__ out){
  __shared__ float al[512];
  __shared__ float red[4];
  int tid = threadIdx.x;
  int b = blockIdx.x >> 3, ch = blockIdx.x & 7;
  for (int t = tid; t < 512; t += 128) al[t] = vu[t*32 + b];
  __syncthreads();
  float m = -1e30f;
  for (int t = tid; t < 512; t += 128) m = fmaxf(m, al[t]);
  #pragma unroll
  for (int o=1;o<64;o<<=1) m = fmaxf(m, __shfl_xor(m,o));
  if ((tid & 63) == 0) red[tid>>6] = m;
  __syncthreads();
  m = fmaxf(red[0], red[1]);
  float s = 0.0f;
  for (int t = tid; t < 512; t += 128){ float e = expf(al[t]-m); al[t] = e; s += e; }
  #pragma unroll
  for (int o=1;o<64;o<<=1) s += __shfl_xor(s,o);
  if ((tid & 63) == 0) red[2 + (tid>>6)] = s;
  __syncthreads();
  float inv = 1.0f / (red[2] + red[3]);
  int n = ch*128 + tid;
  float acc = 0.0f;
  #pragma unroll 4
  for (int t = 0; t < 512; ++t) acc += al[t]*h1[(size_t)(t*32+b)*1024 + n];
  out[b*1024 + n] = acc*inv*ss[n] + ss[1024+n];
}

// ---------------------------------------------------------------------------
extern "C" void kernel_launch(void* const* d_in, const int* in_sizes, int n_in,
                              void* d_out, int out_size, void* d_ws, size_t ws_size,
                              hipStream_t stream){
  const float* x    = (const float*)d_in[0];
  const float* bn1g = (const float*)d_in[1];
  const float* bn1b = (const float*)d_in[2];
  const float* bn2g = (const float*)d_in[3];
  const float* bn2b = (const float*)d_in[4];
  const float* wih0 = (const float*)d_in[5];
  const float* whh0 = (const float*)d_in[6];
  const float* gg0  = (const float*)d_in[7];
  const float* gb0  = (const float*)d_in[8];
  const float* cg0  = (const float*)d_in[9];
  const float* cb0  = (const float*)d_in[10];
  const float* wih1 = (const float*)d_in[11];
  const float* whh1 = (const float*)d_in[12];
  const float* gg1  = (const float*)d_in[13];
  const float* gb1  = (const float*)d_in[14];
  const float* cg1  = (const float*)d_in[15];
  const float* cb1  = (const float*)d_in[16];
  const float* wom  = (const float*)d_in[17];
  const float* bom  = (const float*)d_in[18];
  const float* uom  = (const float*)d_in[19];
  float* out = (float*)d_out;

  char* w = (char*)d_ws;
  size_t off = 0;
  auto take = [&](size_t bytes)->void*{
    void* p = w + off;
    off += (bytes + 255) & ~(size_t)255;
    return p;
  };
  _Float16* xp = (_Float16*)take(16384ull*4096*2);      // 128 MB
  float* hA = (float*)take(16384ull*1024*4);            // 64 MB
  __hip_bfloat16* w0hi = (__hip_bfloat16*)take(4096ull*128*2);
  __hip_bfloat16* w0lo = (__hip_bfloat16*)take(4096ull*128*2);
  __hip_bfloat16* w1hi = (__hip_bfloat16*)take(4096ull*1024*2);
  __hip_bfloat16* w1lo = (__hip_bfloat16*)take(4096ull*1024*2);
  _Float16* wpk0 = (_Float16*)take(2ull*2048*512*2);    // 4 MB
  _Float16* wpk1 = (_Float16*)take(2ull*2048*512*2);    // 4 MB
  float* tilesf = (float*)take(16ull*2*8*CHUNK*4);      // ~1.06 MB
  unsigned* flags = (unsigned*)take(128ull*64*4);       // 32 KB
  float* stats1 = (float*)take(256*4);
  float* ss1    = (float*)take(256*4);
  float* stats2 = (float*)take(2048*4);
  float* ss2    = (float*)take(2048*4);
  float* vu     = (float*)take(16384ull*4);
  (void)ws_size; (void)in_sizes; (void)n_in; (void)out_size;

  hipMemsetAsync(stats1, 0, 256*4, stream);
  hipMemsetAsync(stats2, 0, 2048*4, stream);

  k_bn1_stats<<<256,256,0,stream>>>(x, stats1);
  k_bn1_fin<<<1,128,0,stream>>>(stats1, bn1g, bn1b, ss1);
  k_cvt_split<<<256,256,0,stream>>>(wih0, w0hi, w0lo, 4096*128);
  k_cvt_split<<<2048,256,0,stream>>>(wih1, w1hi, w1lo, 4096*1024);
  k_pack_whh<<<8192,256,0,stream>>>(whh0, wpk0);
  k_pack_whh<<<8192,256,0,stream>>>(whh1, wpk1);

  // GEMM0: xp = bn1(x) @ w_ih0^T
  gemm_split<<<dim3(32,128),256,0,stream>>>(x, w0hi, w0lo, xp, 16384, 4096, 128, 1, ss1);

  // ---- layer 0 ----
  hipMemsetAsync(flags, 0, 128*64*4, stream);
  lstm_fast<<<128,512,0,stream>>>(xp, wpk0, gg0, gb0, cg0, cb0, hA, tilesf, flags);

  // GEMM1: xp = h0 @ w_ih1^T
  gemm_split<<<dim3(32,128),256,0,stream>>>(hA, w1hi, w1lo, xp, 16384, 4096, 1024, 0, nullptr);

  // ---- layer 1 ----
  hipMemsetAsync(flags, 0, 128*64*4, stream);
  lstm_fast<<<128,512,0,stream>>>(xp, wpk1, gg1, gb1, cg1, cb1, hA, tilesf, flags);

  k_bn2_stats<<<256,256,0,stream>>>(hA, stats2);
  k_bn2_fin<<<4,256,0,stream>>>(stats2, bn2g, bn2b, ss2);
  k_att1<<<1024,256,0,stream>>>(hA, ss2, wom, bom, uom, vu);
  k_att3<<<256,128,0,stream>>>(hA, ss2, vu, out);
}